// Round 3
// baseline (641.659 us; speedup 1.0000x reference)
//
#include <hip/hip_runtime.h>
#include <stdint.h>

// ---------------------------------------------------------------------------
// RichAttention: out = softmax(QK^T - w*cdist(coords)) @ V, attn also output.
// B=8, S=2048, H=768, fp32 in/out.
// R3: G-trick: scores = X*(Wq^T Wk)*Y^T  (skip Q/K projections entirely).
//     Bias-exact via rank-1 corrections (rowadd/coladd). k_pv reads fp16 attn
//     copy written by k_rowsoft. k_scores = proven R1 128^2 body.
// ---------------------------------------------------------------------------

typedef _Float16 half8 __attribute__((ext_vector_type(8)));
typedef _Float16 half4v __attribute__((ext_vector_type(4)));
typedef float f32x4 __attribute__((ext_vector_type(4)));

#define DEVI static __device__ __forceinline__

constexpr int B_ = 8, S_ = 2048, H_ = 768;
constexpr long NX = (long)B_ * S_ * H_;   // 12,582,912
constexpr long NW = (long)H_ * H_;        // 589,824
constexpr long ATT = (long)B_ * S_ * S_;  // 33,554,432

// ---- async global->LDS, 16B per lane --------------------------------------
DEVI void glds16(const void* g, void* l) {
  __builtin_amdgcn_global_load_lds(
      (const __attribute__((address_space(1))) uint32_t*)g,
      (__attribute__((address_space(3))) uint32_t*)l, 16, 0, 0);
}

// Stage a [128][32]-fp16 tile (8KB). LDS slot (r,c) holds global chunk
// c ^ ((r>>1)&3)  (chunk = 16B). 256 threads x 2 units.
DEVI void stage_tile(const _Float16* gbase, int rowStride, _Float16* lds, int tid) {
#pragma unroll
  for (int seg = 0; seg < 2; ++seg) {
    int u = seg * 256 + tid;
    int r = u >> 2, c = u & 3;
    int sc = c ^ ((r >> 1) & 3);
    glds16(gbase + (long)r * rowStride + sc * 8, lds + ((u & ~63) << 3));
  }
}

// MFMA 16x16x32 A/B fragment read (undoes the chunk swizzle).
DEVI half8 frag(const _Float16* lds, int m0, int lane) {
  int row = m0 + (lane & 15);
  int c = (lane >> 4) ^ ((row >> 1) & 3);
  return *(const half8*)(lds + row * 32 + c * 8);
}

// ---------------------------------------------------------------------------
// K_uv: u = Wq^T*bk, vv = Wk^T*bq, c = bq.bk   (bias corrections; tiny)
// ---------------------------------------------------------------------------
__global__ __launch_bounds__(128) void k_uv(const float* __restrict__ wq,
                                            const float* __restrict__ wk,
                                            const float* __restrict__ bq,
                                            const float* __restrict__ bk,
                                            float* u, float* vv, float* cb) {
  int i = blockIdx.x * 128 + threadIdx.x;
  if (blockIdx.y == 0) {
    float a = 0;
    for (int j = 0; j < H_; ++j) a += wq[(long)j * H_ + i] * bk[j];
    u[i] = a;
    if (i == 0) {
      float c = 0;
      for (int j = 0; j < H_; ++j) c += bq[j] * bk[j];
      cb[0] = c;
    }
  } else {
    float a = 0;
    for (int j = 0; j < H_; ++j) a += wk[(long)j * H_ + i] * bq[j];
    vv[i] = a;
  }
}

// ---------------------------------------------------------------------------
// K_split: split queries->Xh/Xl (d_out scratch), keys->Yh/Yl (ws),
//          Wq,Wk->hi/lo (d_out scratch).
// ---------------------------------------------------------------------------
__global__ __launch_bounds__(256) void k_split(
    const float* __restrict__ xq, const float* __restrict__ xk,
    const float* __restrict__ wq, const float* __restrict__ wk,
    _Float16* __restrict__ xh, _Float16* __restrict__ xl,
    _Float16* __restrict__ yh, _Float16* __restrict__ yl,
    _Float16* __restrict__ wqh, _Float16* __restrict__ wql,
    _Float16* __restrict__ wkh, _Float16* __restrict__ wkl) {
  const long NX4 = NX / 4, NW4 = NW / 4, TOT = 2 * NX4 + 2 * NW4;
  for (long t = (long)blockIdx.x * blockDim.x + threadIdx.x; t < TOT;
       t += (long)gridDim.x * blockDim.x) {
    const float4* src;
    _Float16 *dh, *dl;
    long idx;
    if (t < NX4) {
      src = (const float4*)xq; dh = xh; dl = xl; idx = t;
    } else if (t < 2 * NX4) {
      src = (const float4*)xk; dh = yh; dl = yl; idx = t - NX4;
    } else {
      long v = t - 2 * NX4;
      if (v < NW4) { src = (const float4*)wq; dh = wqh; dl = wql; idx = v; }
      else { src = (const float4*)wk; dh = wkh; dl = wkl; idx = v - NW4; }
    }
    float4 x = src[idx];
    half4v hi, lo;
    hi[0] = (_Float16)x.x; lo[0] = (_Float16)(x.x - (float)hi[0]);
    hi[1] = (_Float16)x.y; lo[1] = (_Float16)(x.y - (float)hi[1]);
    hi[2] = (_Float16)x.z; lo[2] = (_Float16)(x.z - (float)hi[2]);
    hi[3] = (_Float16)x.w; lo[3] = (_Float16)(x.w - (float)hi[3]);
    *(half4v*)(dh + idx * 4) = hi;
    *(half4v*)(dl + idx * 4) = lo;
  }
}

// ---------------------------------------------------------------------------
// K_tr: transpose 4 contiguous 768x768 fp16 matrices (WqH,WqL,WkH,WkL).
// ---------------------------------------------------------------------------
__global__ __launch_bounds__(256) void k_tr(const _Float16* __restrict__ in,
                                            _Float16* __restrict__ out) {
  const int z = blockIdx.z;
  const _Float16* src = in + (long)z * NW;
  _Float16* dst = out + (long)z * NW;
  __shared__ _Float16 t[64][72];
  int r0 = blockIdx.y * 64, c0 = blockIdx.x * 64;
#pragma unroll
  for (int it = 0; it < 2; ++it) {
    int idx = it * 256 + threadIdx.x;
    int r = idx >> 3, ch = idx & 7;
    *(half8*)&t[r][ch * 8] = *(const half8*)(src + (long)(r0 + r) * H_ + c0 + ch * 8);
  }
  __syncthreads();
#pragma unroll
  for (int it = 0; it < 2; ++it) {
    int idx = it * 256 + threadIdx.x;
    int r = idx >> 3, ch = idx & 7;
    half8 v;
#pragma unroll
    for (int k = 0; k < 8; ++k) v[k] = t[ch * 8 + k][r];
    *(half8*)(dst + (long)(c0 + r) * H_ + r0 + ch * 8) = v;
  }
}

// ---------------------------------------------------------------------------
// K_dot: dst[row] = dot(src[row,:768], vec) (+c). rowadd/coladd GEMVs.
// ---------------------------------------------------------------------------
__global__ __launch_bounds__(256) void k_dot(const float* __restrict__ src,
                                             const float* __restrict__ vec,
                                             const float* __restrict__ cb,
                                             float* __restrict__ dst, int addc) {
  int wid = threadIdx.x >> 6, lane = threadIdx.x & 63;
  long row = (long)blockIdx.x * 4 + wid;
  const float4* p = (const float4*)(src + row * H_);
  const float4* q = (const float4*)vec;
  float s = 0;
#pragma unroll
  for (int k = 0; k < 3; ++k) {
    float4 a = p[lane + k * 64], b = q[lane + k * 64];
    s += a.x * b.x + a.y * b.y + a.z * b.z + a.w * b.w;
  }
#pragma unroll
  for (int o = 32; o; o >>= 1) s += __shfl_xor(s, o);
  if (lane == 0) dst[row] = s + (addc ? cb[0] : 0.0f);
}

// ---------------------------------------------------------------------------
// K_gemm3: C = A.B^T via 3-term split (AhBh+AhBl+AlBh), 128^2 tile, K=768,
// split-write Oh/Ol. Used for Gt = WkT.WqT^T (grid 6x6) and P = X.Gt^T
// (grid 6x128). All strides 768.  [R1-proven body]
// ---------------------------------------------------------------------------
__global__ __launch_bounds__(256, 2) void k_gemm3(
    const _Float16* __restrict__ Ah_, const _Float16* __restrict__ Al_,
    const _Float16* __restrict__ Bh_, const _Float16* __restrict__ Bl_,
    _Float16* __restrict__ Oh, _Float16* __restrict__ Ol) {
  const int nt = blockIdx.x, mt = blockIdx.y;
  const int tid = threadIdx.x;
  __shared__ _Float16 sm[2][4][4096];
  f32x4 acc[4][4] = {};
  const _Float16* Ah = Ah_ + (long)(mt * 128) * H_;
  const _Float16* Al = Al_ + (long)(mt * 128) * H_;
  const _Float16* Bh = Bh_ + (long)(nt * 128) * H_;
  const _Float16* Bl = Bl_ + (long)(nt * 128) * H_;

  stage_tile(Ah, H_, sm[0][0], tid);
  stage_tile(Bh, H_, sm[0][2], tid);
  stage_tile(Al, H_, sm[0][1], tid);
  stage_tile(Bl, H_, sm[0][3], tid);
  __syncthreads();

  const int lane = tid & 63, wid = tid >> 6;
  const int wm = (wid >> 1) * 64, wn = (wid & 1) * 64;

  int cur = 0;
  for (int kk = 0; kk < 24; ++kk) {
    if (kk + 1 < 24) {
      int o = (kk + 1) * 32;
      stage_tile(Ah + o, H_, sm[cur ^ 1][0], tid);
      stage_tile(Bh + o, H_, sm[cur ^ 1][2], tid);
      stage_tile(Al + o, H_, sm[cur ^ 1][1], tid);
      stage_tile(Bl + o, H_, sm[cur ^ 1][3], tid);
    }
    half8 ah[4], bh[4], al[4], bl[4];
#pragma unroll
    for (int i = 0; i < 4; ++i) {
      ah[i] = frag(sm[cur][0], wm + i * 16, lane);
      al[i] = frag(sm[cur][1], wm + i * 16, lane);
    }
#pragma unroll
    for (int j = 0; j < 4; ++j) {
      bh[j] = frag(sm[cur][2], wn + j * 16, lane);
      bl[j] = frag(sm[cur][3], wn + j * 16, lane);
    }
#pragma unroll
    for (int i = 0; i < 4; ++i)
#pragma unroll
      for (int j = 0; j < 4; ++j) {
        acc[i][j] = __builtin_amdgcn_mfma_f32_16x16x32_f16(ah[i], bh[j],
                                                           acc[i][j], 0, 0, 0);
        acc[i][j] = __builtin_amdgcn_mfma_f32_16x16x32_f16(ah[i], bl[j],
                                                           acc[i][j], 0, 0, 0);
        acc[i][j] = __builtin_amdgcn_mfma_f32_16x16x32_f16(al[i], bh[j],
                                                           acc[i][j], 0, 0, 0);
      }
    __syncthreads();
    cur ^= 1;
  }

#pragma unroll
  for (int i = 0; i < 4; ++i) {
    int m_t = wm + i * 16 + ((lane >> 4) << 2);
#pragma unroll
    for (int j = 0; j < 4; ++j) {
      int n_t = wn + j * 16 + (lane & 15);
      int gn = nt * 128 + n_t;
#pragma unroll
      for (int r = 0; r < 4; ++r) {
        long gm = (long)mt * 128 + m_t + r;
        float y = acc[i][j][r];
        _Float16 hi = (_Float16)y;
        Oh[gm * H_ + gn] = hi;
        Ol[gm * H_ + gn] = (_Float16)(y - (float)hi);
      }
    }
  }
}

// ---------------------------------------------------------------------------
// K_scores: raw scores = P.Y^T (3-term) - w*dist + rowadd + coladd.
// R1-proven 128^2 body.
// ---------------------------------------------------------------------------
__global__ __launch_bounds__(256, 2) void k_scores(
    const _Float16* __restrict__ ph, const _Float16* __restrict__ pl,
    const _Float16* __restrict__ yh, const _Float16* __restrict__ yl,
    const float* __restrict__ coords, const float* __restrict__ sw,
    const float* __restrict__ rowadd, const float* __restrict__ coladd,
    float* __restrict__ attn) {
  const int nt = blockIdx.x, mt = blockIdx.y, b = blockIdx.z;
  const int tid = threadIdx.x;
  __shared__ _Float16 sm[2][4][4096];
  __shared__ float cr[2][128], cc[2][128], ra[128], ca[128];

  if (tid < 128) {
    long gi = (long)b * S_ + mt * 128 + tid;
    cr[0][tid] = coords[gi * 2 + 0];
    cr[1][tid] = coords[gi * 2 + 1];
    ra[tid] = rowadd[gi];
  } else {
    int t = tid - 128;
    long gj = (long)b * S_ + nt * 128 + t;
    cc[0][t] = coords[gj * 2 + 0];
    cc[1][t] = coords[gj * 2 + 1];
    ca[t] = coladd[gj];
  }
  const float w = sw[0];

  f32x4 acc[4][4] = {};
  const long aoff = ((long)b * S_ + mt * 128) * H_;
  const long boff = ((long)b * S_ + nt * 128) * H_;
  const _Float16* Ah = ph + aoff;
  const _Float16* Al = pl + aoff;
  const _Float16* Bh = yh + boff;
  const _Float16* Bl = yl + boff;

  stage_tile(Ah, H_, sm[0][0], tid);
  stage_tile(Al, H_, sm[0][1], tid);
  stage_tile(Bh, H_, sm[0][2], tid);
  stage_tile(Bl, H_, sm[0][3], tid);
  __syncthreads();

  const int lane = tid & 63, wid = tid >> 6;
  const int wm = (wid >> 1) * 64, wn = (wid & 1) * 64;

  int cur = 0;
  for (int kk = 0; kk < 24; ++kk) {
    if (kk + 1 < 24) {
      int o = (kk + 1) * 32;
      stage_tile(Ah + o, H_, sm[cur ^ 1][0], tid);
      stage_tile(Al + o, H_, sm[cur ^ 1][1], tid);
      stage_tile(Bh + o, H_, sm[cur ^ 1][2], tid);
      stage_tile(Bl + o, H_, sm[cur ^ 1][3], tid);
    }
    half8 ah[4], al4[4], bh[4], bl4[4];
#pragma unroll
    for (int i = 0; i < 4; ++i) {
      ah[i] = frag(sm[cur][0], wm + i * 16, lane);
      al4[i] = frag(sm[cur][1], wm + i * 16, lane);
    }
#pragma unroll
    for (int j = 0; j < 4; ++j) {
      bh[j] = frag(sm[cur][2], wn + j * 16, lane);
      bl4[j] = frag(sm[cur][3], wn + j * 16, lane);
    }
#pragma unroll
    for (int i = 0; i < 4; ++i)
#pragma unroll
      for (int j = 0; j < 4; ++j) {
        acc[i][j] = __builtin_amdgcn_mfma_f32_16x16x32_f16(ah[i], bh[j],
                                                           acc[i][j], 0, 0, 0);
        acc[i][j] = __builtin_amdgcn_mfma_f32_16x16x32_f16(ah[i], bl4[j],
                                                           acc[i][j], 0, 0, 0);
        acc[i][j] = __builtin_amdgcn_mfma_f32_16x16x32_f16(al4[i], bh[j],
                                                           acc[i][j], 0, 0, 0);
      }
    __syncthreads();
    cur ^= 1;
  }

#pragma unroll
  for (int i = 0; i < 4; ++i) {
    int m_t = wm + i * 16 + ((lane >> 4) << 2);
#pragma unroll
    for (int j = 0; j < 4; ++j) {
      int n_t = wn + j * 16 + (lane & 15);
      float cjx = cc[0][n_t], cjy = cc[1][n_t];
      long rowbase = ((long)b * S_ + mt * 128 + m_t) * S_ + nt * 128 + n_t;
#pragma unroll
      for (int r = 0; r < 4; ++r) {
        float dx = cr[0][m_t + r] - cjx;
        float dy = cr[1][m_t + r] - cjy;
        float d = sqrtf(fmaxf(fmaf(dx, dx, dy * dy), 1e-12f));
        attn[rowbase + (long)r * S_] = acc[i][j][r] - w * d + ra[m_t + r] + ca[n_t];
      }
    }
  }
}

// ---------------------------------------------------------------------------
// K_rowsoft: row softmax in place (fp32) + write normalized fp16 copy.
// ---------------------------------------------------------------------------
__global__ __launch_bounds__(256) void k_rowsoft(float* __restrict__ attn,
                                                 _Float16* __restrict__ a16) {
  const int wid = threadIdx.x >> 6, lane = threadIdx.x & 63;
  long row = (long)blockIdx.x * 4 + wid;
  float* p = attn + row * S_;
  _Float16* p16 = a16 + row * S_;
  float4 v[8];
#pragma unroll
  for (int i = 0; i < 8; ++i) v[i] = ((const float4*)p)[i * 64 + lane];
  float m = -3.4e38f;
#pragma unroll
  for (int i = 0; i < 8; ++i)
    m = fmaxf(m, fmaxf(fmaxf(v[i].x, v[i].y), fmaxf(v[i].z, v[i].w)));
#pragma unroll
  for (int o = 32; o > 0; o >>= 1) m = fmaxf(m, __shfl_xor(m, o));
  float l = 0.f;
#pragma unroll
  for (int i = 0; i < 8; ++i) {
    v[i].x = __expf(v[i].x - m);
    v[i].y = __expf(v[i].y - m);
    v[i].z = __expf(v[i].z - m);
    v[i].w = __expf(v[i].w - m);
    l += (v[i].x + v[i].y) + (v[i].z + v[i].w);
  }
#pragma unroll
  for (int o = 32; o > 0; o >>= 1) l += __shfl_xor(l, o);
  const float rl = 1.0f / l;
#pragma unroll
  for (int i = 0; i < 8; ++i) {
    v[i].x *= rl; v[i].y *= rl; v[i].z *= rl; v[i].w *= rl;
    ((float4*)p)[i * 64 + lane] = v[i];
    half4v h = {(_Float16)v[i].x, (_Float16)v[i].y, (_Float16)v[i].z,
                (_Float16)v[i].w};
    ((half4v*)p16)[i * 64 + lane] = h;
  }
}

// ---------------------------------------------------------------------------
// K_projv: v = values.Wv^T + bv, written TRANSPOSED vT[b][h][t] fp16.
// Both operands reg-staged fp32->fp16 (issue-early / write-late).
// ---------------------------------------------------------------------------
__global__ __launch_bounds__(256, 2) void k_projv(
    const float* __restrict__ vals, const float* __restrict__ wv,
    const float* __restrict__ bv, _Float16* __restrict__ vT) {
  const int nt = blockIdx.x, mt = blockIdx.y;
  const int tid = threadIdx.x, lane = tid & 63, wid = tid >> 6;
  const int wm = (wid >> 1) * 64, wn = (wid & 1) * 64;
  __shared__ _Float16 sm[2][2][4096];
  f32x4 acc[4][4] = {};
  const float* Ab = vals + (long)(mt * 128) * H_;
  const float* Bb = wv + (long)(nt * 128) * H_;

#pragma unroll
  for (int op = 0; op < 2; ++op) {
    const float* gb = op ? Bb : Ab;
#pragma unroll
    for (int seg = 0; seg < 2; ++seg) {
      int u = seg * 256 + tid, r = u >> 2, c = u & 3;
      int sc = c ^ ((r >> 1) & 3);
      const float4* s4 = (const float4*)(gb + (long)r * H_ + sc * 8);
      float4 x0 = s4[0], x1 = s4[1];
      half8 h = {(_Float16)x0.x, (_Float16)x0.y, (_Float16)x0.z, (_Float16)x0.w,
                 (_Float16)x1.x, (_Float16)x1.y, (_Float16)x1.z, (_Float16)x1.w};
      *(half8*)(&sm[0][op][r * 32 + c * 8]) = h;
    }
  }
  __syncthreads();

  int cur = 0;
  for (int kk = 0; kk < 24; ++kk) {
    float4 pa[2][2], pb[2][2];
    const bool pre = (kk + 1 < 24);
    if (pre) {
#pragma unroll
      for (int seg = 0; seg < 2; ++seg) {
        int u = seg * 256 + tid, r = u >> 2;
        int sc = (u & 3) ^ ((r >> 1) & 3);
        const float4* s4 = (const float4*)(Ab + (long)r * H_ + (kk + 1) * 32 + sc * 8);
        pa[seg][0] = s4[0]; pa[seg][1] = s4[1];
        const float4* t4 = (const float4*)(Bb + (long)r * H_ + (kk + 1) * 32 + sc * 8);
        pb[seg][0] = t4[0]; pb[seg][1] = t4[1];
      }
    }
    half8 ah[4], bh[4];
#pragma unroll
    for (int i = 0; i < 4; ++i) ah[i] = frag(sm[cur][0], wm + i * 16, lane);
#pragma unroll
    for (int j = 0; j < 4; ++j) bh[j] = frag(sm[cur][1], wn + j * 16, lane);
#pragma unroll
    for (int i = 0; i < 4; ++i)
#pragma unroll
      for (int j = 0; j < 4; ++j)
        acc[i][j] = __builtin_amdgcn_mfma_f32_16x16x32_f16(ah[i], bh[j],
                                                           acc[i][j], 0, 0, 0);
    if (pre) {
#pragma unroll
      for (int op = 0; op < 2; ++op) {
#pragma unroll
        for (int seg = 0; seg < 2; ++seg) {
          int u = seg * 256 + tid, r = u >> 2, c = u & 3;
          float4 x0 = op ? pb[seg][0] : pa[seg][0];
          float4 x1 = op ? pb[seg][1] : pa[seg][1];
          half8 h = {(_Float16)x0.x, (_Float16)x0.y, (_Float16)x0.z,
                     (_Float16)x0.w, (_Float16)x1.x, (_Float16)x1.y,
                     (_Float16)x1.z, (_Float16)x1.w};
          *(half8*)(&sm[cur ^ 1][op][r * 32 + c * 8]) = h;
        }
      }
    }
    __syncthreads();
    cur ^= 1;
  }

#pragma unroll
  for (int i = 0; i < 4; ++i) {
    int m_t = wm + i * 16 + ((lane >> 4) << 2);
#pragma unroll
    for (int j = 0; j < 4; ++j) {
      int n_t = wn + j * 16 + (lane & 15);
      int gn = nt * 128 + n_t;
      float bs = bv[gn];
      int gmI = mt * 128 + m_t;
      int bb = gmI >> 11, t0 = gmI & 2047;
      half4v pk;
#pragma unroll
      for (int r = 0; r < 4; ++r) pk[r] = (_Float16)(acc[i][j][r] + bs);
      *(half4v*)&vT[((long)bb * H_ + gn) * S_ + t0] = pk;
    }
  }
}

// ---------------------------------------------------------------------------
// K_pv16: out = attn16 @ vT^T. Pure global_load_lds pipeline, K=2048.
// ---------------------------------------------------------------------------
__global__ __launch_bounds__(256, 2) void k_pv16(
    const _Float16* __restrict__ a16, const _Float16* __restrict__ vT,
    float* __restrict__ outp) {
  const int nt = blockIdx.x, mt = blockIdx.y, b = blockIdx.z;
  const int tid = threadIdx.x, lane = tid & 63, wid = tid >> 6;
  const int wm = (wid >> 1) * 64, wn = (wid & 1) * 64;
  __shared__ _Float16 sm[2][2][4096];
  f32x4 acc[4][4] = {};
  const _Float16* Ab = a16 + ((long)b * S_ + mt * 128) * S_;
  const _Float16* Bb = vT + ((long)b * H_ + nt * 128) * S_;

  stage_tile(Ab, S_, sm[0][0], tid);
  stage_tile(Bb, S_, sm[0][1], tid);
  __syncthreads();

  int cur = 0;
  for (int kk = 0; kk < 64; ++kk) {
    if (kk + 1 < 64) {
      stage_tile(Ab + (kk + 1) * 32, S_, sm[cur ^ 1][0], tid);
      stage_tile(Bb + (kk + 1) * 32, S_, sm[cur ^ 1][1], tid);
    }
    half8 ah[4], bh[4];
#pragma unroll
    for (int i = 0; i < 4; ++i) ah[i] = frag(sm[cur][0], wm + i * 16, lane);
#pragma unroll
    for (int j = 0; j < 4; ++j) bh[j] = frag(sm[cur][1], wn + j * 16, lane);
#pragma unroll
    for (int i = 0; i < 4; ++i)
#pragma unroll
      for (int j = 0; j < 4; ++j)
        acc[i][j] = __builtin_amdgcn_mfma_f32_16x16x32_f16(ah[i], bh[j],
                                                           acc[i][j], 0, 0, 0);
    __syncthreads();
    cur ^= 1;
  }

#pragma unroll
  for (int i = 0; i < 4; ++i) {
    int m_t = wm + i * 16 + ((lane >> 4) << 2);
#pragma unroll
    for (int j = 0; j < 4; ++j) {
      int n_t = wn + j * 16 + (lane & 15);
      int h = nt * 128 + n_t;
      long rowbase = (long)b * S_ + mt * 128 + m_t;
#pragma unroll
      for (int r = 0; r < 4; ++r) outp[(rowbase + r) * H_ + h] = acc[i][j][r];
    }
  }
}

// ---------------------------------------------------------------------------
extern "C" void kernel_launch(void* const* d_in, const int* in_sizes, int n_in,
                              void* d_out, int out_size, void* d_ws,
                              size_t ws_size, hipStream_t stream) {
  const float* xq = (const float*)d_in[0];
  const float* xk = (const float*)d_in[1];
  const float* xv = (const float*)d_in[2];
  const float* co = (const float*)d_in[3];
  const float* wq = (const float*)d_in[4];
  const float* bq = (const float*)d_in[5];
  const float* wk = (const float*)d_in[6];
  const float* bk = (const float*)d_in[7];
  const float* wv = (const float*)d_in[8];
  const float* bv = (const float*)d_in[9];
  const float* sw = (const float*)d_in[10];

  float* out = (float*)d_out;
  float* attn = out + NX;

  // d_out scratch (dead before k_scores writes attn):
  _Float16* sc = (_Float16*)d_out;
  _Float16* Xh = sc;             // queries hi
  _Float16* Xl = sc + NX;        // queries lo
  _Float16* Wbase = sc + 2 * NX; // WqH,WqL,WkH,WkL
  _Float16* WT = Wbase + 4 * NW; // WqTH,WqTL,WkTH,WkTL
  _Float16* GtH = Wbase + 8 * NW;
  _Float16* GtL = GtH + NW;

  // ws: Ph,Pl,Yh,Yl (phase 1) -> reused as attn16+vT (phase 2); extras tail.
  _Float16* wsh = (_Float16*)d_ws;
  _Float16* Ph = wsh;
  _Float16* Pl = wsh + NX;
  _Float16* Yh = wsh + 2 * NX;
  _Float16* Yl = wsh + 3 * NX;
  float* extras = (float*)(wsh + 4 * NX);
  float* rowadd = extras;
  float* coladd = extras + 16384;
  float* u = extras + 32768;
  float* vv = u + H_;
  float* cb = vv + H_;
  _Float16* a16 = wsh;        // aliases Ph/Pl (dead after k_scores)
  _Float16* vT = wsh + ATT;   // aliases Yh/Yl tail (dead after k_scores)

  k_uv<<<dim3(6, 2), 128, 0, stream>>>(wq, wk, bq, bk, u, vv, cb);
  k_split<<<2048, 256, 0, stream>>>(xq, xk, wq, wk, Xh, Xl, Yh, Yl, Wbase,
                                    Wbase + NW, Wbase + 2 * NW, Wbase + 3 * NW);
  k_tr<<<dim3(12, 12, 4), 256, 0, stream>>>(Wbase, WT);
  // Gt = WkT . (WqT)^T : A = WkT(h,l), Bt = WqT(h,l)
  k_gemm3<<<dim3(6, 6), 256, 0, stream>>>(WT + 2 * NW, WT + 3 * NW, WT,
                                          WT + NW, GtH, GtL);
  k_dot<<<4096, 256, 0, stream>>>(xq, u, cb, rowadd, 1);
  k_dot<<<4096, 256, 0, stream>>>(xk, vv, cb, coladd, 0);
  // P = X . Gt^T
  k_gemm3<<<dim3(6, 128), 256, 0, stream>>>(Xh, Xl, GtH, GtL, Ph, Pl);
  k_scores<<<dim3(16, 16, 8), 256, 0, stream>>>(Ph, Pl, Yh, Yl, co, sw, rowadd,
                                                coladd, attn);
  k_rowsoft<<<4096, 256, 0, stream>>>(attn, a16);
  k_projv<<<dim3(6, 128), 256, 0, stream>>>(xv, wv, bv, vT);
  k_pv16<<<dim3(6, 16, 8), 256, 0, stream>>>(a16, vT, out);
}

// Round 4
// 553.913 us; speedup vs baseline: 1.1584x; 1.1584x over previous
//
#include <hip/hip_runtime.h>
#include <stdint.h>

// ---------------------------------------------------------------------------
// RichAttention: out = softmax(QK^T - w*cdist(coords)) @ V, attn also output.
// B=8, S=2048, H=768, fp32 in/out.
// R4 = R1-proven pipeline (557us) with ONLY k_scores replaced by an 8-phase
// 256x256 counted-vmcnt schedule (T3+T4+T5). Everything else verbatim R1.
// ---------------------------------------------------------------------------

typedef _Float16 half8 __attribute__((ext_vector_type(8)));
typedef _Float16 half4v __attribute__((ext_vector_type(4)));
typedef float f32x4 __attribute__((ext_vector_type(4)));

#define DEVI static __device__ __forceinline__

constexpr int B_ = 8, S_ = 2048, H_ = 768;
constexpr long NX = (long)B_ * S_ * H_;  // 12,582,912
constexpr long NW = (long)H_ * H_;       // 589,824

// ---- async global->LDS, 16B per lane --------------------------------------
DEVI void glds16(const void* g, void* l) {
  __builtin_amdgcn_global_load_lds(
      (const __attribute__((address_space(1))) uint32_t*)g,
      (__attribute__((address_space(3))) uint32_t*)l, 16, 0, 0);
}

// Stage a [128][32]-fp16 tile (8KB). LDS slot (r,c) holds global chunk
// c ^ ((r>>1)&3). 256 threads x 2 units.
DEVI void stage_tile(const _Float16* gbase, int rowStride, _Float16* lds, int tid) {
#pragma unroll
  for (int seg = 0; seg < 2; ++seg) {
    int u = seg * 256 + tid;
    int r = u >> 2, c = u & 3;
    int sc = c ^ ((r >> 1) & 3);
    glds16(gbase + (long)r * rowStride + sc * 8, lds + ((u & ~63) << 3));
  }
}

// MFMA 16x16x32 A/B fragment read (undoes the chunk swizzle).
DEVI half8 frag(const _Float16* lds, int m0, int lane) {
  int row = m0 + (lane & 15);
  int c = (lane >> 4) ^ ((row >> 1) & 3);
  return *(const half8*)(lds + row * 32 + c * 8);
}

// ---------------------------------------------------------------------------
// K0: split inputs (queries/keys/values) and weights into fp16 hi/lo pairs.
// Destination: d_out used as scratch (dead until k_scores writes attn).
// ---------------------------------------------------------------------------
__global__ __launch_bounds__(256) void k_split(
    const float* __restrict__ xq, const float* __restrict__ xk,
    const float* __restrict__ xv, const float* __restrict__ wq,
    const float* __restrict__ wk, const float* __restrict__ wv,
    _Float16* __restrict__ dst) {
  const long NX4 = NX / 4, NW4 = NW / 4, TOT = 3 * NX4 + 3 * NW4;
  for (long u = (long)blockIdx.x * blockDim.x + threadIdx.x; u < TOT;
       u += (long)gridDim.x * blockDim.x) {
    const float4* src;
    _Float16 *dh, *dl;
    long idx;
    if (u < 3 * NX4) {
      int z = (u >= 2 * NX4) ? 2 : (u >= NX4) ? 1 : 0;
      idx = u - (long)z * NX4;
      src = (const float4*)(z == 0 ? xq : z == 1 ? xk : xv);
      dh = dst + (long)z * 2 * NX;
      dl = dh + NX;
    } else {
      long t = u - 3 * NX4;
      int z = (t >= 2 * NW4) ? 2 : (t >= NW4) ? 1 : 0;
      idx = t - (long)z * NW4;
      src = (const float4*)(z == 0 ? wq : z == 1 ? wk : wv);
      dh = dst + 6 * NX + (long)z * 2 * NW;
      dl = dh + NW;
    }
    float4 x = src[idx];
    half4v hi, lo;
    hi[0] = (_Float16)x.x; lo[0] = (_Float16)(x.x - (float)hi[0]);
    hi[1] = (_Float16)x.y; lo[1] = (_Float16)(x.y - (float)hi[1]);
    hi[2] = (_Float16)x.z; lo[2] = (_Float16)(x.z - (float)hi[2]);
    hi[3] = (_Float16)x.w; lo[3] = (_Float16)(x.w - (float)hi[3]);
    *(half4v*)(dh + idx * 4) = hi;
    *(half4v*)(dl + idx * 4) = lo;
  }
}

// ---------------------------------------------------------------------------
// K1: projections Y = X @ W^T + b. z=0: Q (hi/lo), z=1: K (hi/lo),
// z=2: V stored TRANSPOSED vT[b][h][t] fp16.  [verbatim R1]
// ---------------------------------------------------------------------------
__global__ __launch_bounds__(256, 2) void k_proj(
    const _Float16* __restrict__ scratch, const float* __restrict__ bq,
    const float* __restrict__ bk, const float* __restrict__ bv,
    _Float16* __restrict__ qh, _Float16* __restrict__ ql,
    _Float16* __restrict__ kh, _Float16* __restrict__ kl,
    _Float16* __restrict__ vT) {
  const int nt = blockIdx.x, mt = blockIdx.y, z = blockIdx.z;
  const int tid = threadIdx.x;
  const bool full = (z < 2);
  const _Float16* Xh = scratch + (long)z * 2 * NX;
  const _Float16* Xl = Xh + NX;
  const _Float16* Wh = scratch + 6 * NX + (long)z * 2 * NW;
  const _Float16* Wl = Wh + NW;
  const float* bias = (z == 0) ? bq : (z == 1) ? bk : bv;

  __shared__ _Float16 sm[2][4][4096];

  f32x4 acc[4][4] = {};

  const _Float16* Ah = Xh + (long)(mt * 128) * H_;
  const _Float16* Al = Xl + (long)(mt * 128) * H_;
  const _Float16* Bh = Wh + (long)(nt * 128) * H_;
  const _Float16* Bl = Wl + (long)(nt * 128) * H_;

  stage_tile(Ah, H_, sm[0][0], tid);
  stage_tile(Bh, H_, sm[0][2], tid);
  if (full) {
    stage_tile(Al, H_, sm[0][1], tid);
    stage_tile(Bl, H_, sm[0][3], tid);
  }
  __syncthreads();

  const int lane = tid & 63, wid = tid >> 6;
  const int wm = (wid >> 1) * 64, wn = (wid & 1) * 64;

  int cur = 0;
  for (int kk = 0; kk < 24; ++kk) {
    if (kk + 1 < 24) {
      int o = (kk + 1) * 32;
      stage_tile(Ah + o, H_, sm[cur ^ 1][0], tid);
      stage_tile(Bh + o, H_, sm[cur ^ 1][2], tid);
      if (full) {
        stage_tile(Al + o, H_, sm[cur ^ 1][1], tid);
        stage_tile(Bl + o, H_, sm[cur ^ 1][3], tid);
      }
    }
    half8 ah[4], bh[4];
#pragma unroll
    for (int i = 0; i < 4; ++i) ah[i] = frag(sm[cur][0], wm + i * 16, lane);
#pragma unroll
    for (int j = 0; j < 4; ++j) bh[j] = frag(sm[cur][2], wn + j * 16, lane);
#pragma unroll
    for (int i = 0; i < 4; ++i)
#pragma unroll
      for (int j = 0; j < 4; ++j)
        acc[i][j] = __builtin_amdgcn_mfma_f32_16x16x32_f16(ah[i], bh[j],
                                                           acc[i][j], 0, 0, 0);
    if (full) {
      half8 al[4], bl[4];
#pragma unroll
      for (int i = 0; i < 4; ++i) al[i] = frag(sm[cur][1], wm + i * 16, lane);
#pragma unroll
      for (int j = 0; j < 4; ++j) bl[j] = frag(sm[cur][3], wn + j * 16, lane);
#pragma unroll
      for (int i = 0; i < 4; ++i)
#pragma unroll
        for (int j = 0; j < 4; ++j) {
          acc[i][j] = __builtin_amdgcn_mfma_f32_16x16x32_f16(ah[i], bl[j],
                                                             acc[i][j], 0, 0, 0);
          acc[i][j] = __builtin_amdgcn_mfma_f32_16x16x32_f16(al[i], bh[j],
                                                             acc[i][j], 0, 0, 0);
        }
    }
    __syncthreads();
    cur ^= 1;
  }

  _Float16* oh = (z == 0) ? qh : kh;
  _Float16* ol = (z == 0) ? ql : kl;
#pragma unroll
  for (int i = 0; i < 4; ++i) {
    int m_t = wm + i * 16 + ((lane >> 4) << 2);
#pragma unroll
    for (int j = 0; j < 4; ++j) {
      int n_t = wn + j * 16 + (lane & 15);
      int gn = nt * 128 + n_t;
      float bs = bias[gn];
      if (z < 2) {
#pragma unroll
        for (int r = 0; r < 4; ++r) {
          long gm = (long)mt * 128 + m_t + r;
          float y = acc[i][j][r] + bs;
          _Float16 hi = (_Float16)y;
          oh[gm * H_ + gn] = hi;
          ol[gm * H_ + gn] = (_Float16)(y - (float)hi);
        }
      } else {
        int gmI = mt * 128 + m_t;
        int bb = gmI >> 11, t0 = gmI & 2047;
        half4v pk;
#pragma unroll
        for (int r = 0; r < 4; ++r) pk[r] = (_Float16)(acc[i][j][r] + bs);
        *(half4v*)&vT[((long)bb * H_ + gn) * S_ + t0] = pk;
      }
    }
  }
}

// ---------------------------------------------------------------------------
// K2 (R4): raw scores = q.k (3-term split-fp16 via virtual-K) - w*dist.
// 256x256 tile, 512 threads (8 waves 2x4, each 128x64 out). Virtual K:
// 36 tiles of 64 (12/term): [0,12)=qh.kh [12,24)=qh.kl [24,36)=ql.kh.
// LDS [2 slots][2 khalf][A,B][256x32] = 128KB. Group g = 4 phases of 16 MFMA
// (khalf x mhalf). Stage tile g+1 chunk-per-phase into freed slot; vmcnt(6)
// only at khalf-boundary phases (never 0 in steady state); raw s_barrier;
// setprio around MFMA clusters.
// ---------------------------------------------------------------------------
__global__ __launch_bounds__(512, 2) void k_scores8(
    const _Float16* __restrict__ qh, const _Float16* __restrict__ ql,
    const _Float16* __restrict__ kh_, const _Float16* __restrict__ kl_,
    const float* __restrict__ coords, const float* __restrict__ sw,
    float* __restrict__ attn) {
  const int nt = blockIdx.x, mt = blockIdx.y, b = blockIdx.z;
  const int tid = threadIdx.x, lane = tid & 63, wid = tid >> 6;
  const int wr = wid >> 2, wc = wid & 3;  // 2x4 waves, each 128x64 out

  __shared__ _Float16 lds[2][2][2][8192];  // [slot][khalf][A,B][256*32]
  __shared__ float cco[4][256];            // rx, ry, cx, cy

  if (tid < 256) {
    long gi = (long)b * S_ + mt * 256 + tid;
    cco[0][tid] = coords[gi * 2 + 0];
    cco[1][tid] = coords[gi * 2 + 1];
  } else {
    int t = tid - 256;
    long gj = (long)b * S_ + nt * 256 + t;
    cco[2][t] = coords[gj * 2 + 0];
    cco[3][t] = coords[gj * 2 + 1];
  }
  const float w = sw[0];

  const long aoff = ((long)b * S_ + mt * 256) * H_;
  const long boff = ((long)b * S_ + nt * 256) * H_;

  // staging offsets: 512 threads x 2 rounds cover 256 rows x 32 cols fp16
  long goff[2];
  int loff[2];
#pragma unroll
  for (int seg = 0; seg < 2; ++seg) {
    int u = seg * 512 + tid;
    int r = u >> 2, c = u & 3;
    int sc = c ^ ((r >> 1) & 3);
    goff[seg] = (long)r * H_ + sc * 8;
    loff[seg] = (u & ~63) << 3;
  }

  f32x4 acc[8][4] = {};

  auto asrc = [&](int kt) -> const _Float16* {
    int term = kt / 12, ko = (kt % 12) * 64;
    return (term == 2 ? ql : qh) + aoff + ko;
  };
  auto bsrc = [&](int kt) -> const _Float16* {
    int term = kt / 12, ko = (kt % 12) * 64;
    return (term == 1 ? kl_ : kh_) + boff + ko;
  };
  // chunk: 0=A.k0 1=B.k0 2=A.k1 3=B.k1  (2 glds16/thread each)
  auto stg = [&](int kt, int chunk) {
    int khf = chunk >> 1, ab = chunk & 1;
    const _Float16* src = (ab ? bsrc(kt) : asrc(kt)) + khf * 32;
    _Float16* dst = &lds[kt & 1][khf][ab][0];
    glds16(src + goff[0], dst + loff[0]);
    glds16(src + goff[1], dst + loff[1]);
  };

  half8 bf[4];  // persists across the mh pair of a khalf

  // phase: optionally stage one chunk of tile (g+1); vm: -1 none, 6/4/0.
  auto do_phase = [&](int slot, int kh, int mh, int sg_kt, int chunk, int vm) {
    const _Float16* A = &lds[slot][kh][0][0];
    const _Float16* Bt = &lds[slot][kh][1][0];
    half8 af[4];
    if (mh == 1) {  // non-boundary: data landed a phase ago; read at top
#pragma unroll
      for (int i = 0; i < 4; ++i)
        af[i] = frag(A, wr * 128 + mh * 64 + i * 16, lane);
    }
    if (sg_kt >= 0) stg(sg_kt, chunk);
    if (vm == 6) asm volatile("s_waitcnt vmcnt(6)" ::: "memory");
    else if (vm == 4) asm volatile("s_waitcnt vmcnt(4)" ::: "memory");
    else if (vm == 0) asm volatile("s_waitcnt vmcnt(0)" ::: "memory");
    __builtin_amdgcn_s_barrier();
    asm volatile("" ::: "memory");
    if (mh == 0) {  // boundary: fresh khalf chunk -> read only after barrier
#pragma unroll
      for (int j = 0; j < 4; ++j) bf[j] = frag(Bt, wc * 64 + j * 16, lane);
#pragma unroll
      for (int i = 0; i < 4; ++i)
        af[i] = frag(A, wr * 128 + mh * 64 + i * 16, lane);
    }
    __builtin_amdgcn_s_setprio(1);
#pragma unroll
    for (int i = 0; i < 4; ++i)
#pragma unroll
      for (int j = 0; j < 4; ++j)
        acc[mh * 4 + i][j] = __builtin_amdgcn_mfma_f32_16x16x32_f16(
            af[i], bf[j], acc[mh * 4 + i][j], 0, 0, 0);
    __builtin_amdgcn_s_setprio(0);
    asm volatile("" ::: "memory");
    __builtin_amdgcn_s_barrier();
    asm volatile("" ::: "memory");
  };

  // prologue: stage tile 0, drain once
  stg(0, 0); stg(0, 1); stg(0, 2); stg(0, 3);
  asm volatile("s_waitcnt vmcnt(0) lgkmcnt(0)" ::: "memory");
  __builtin_amdgcn_s_barrier();
  asm volatile("" ::: "memory");

#pragma unroll 1
  for (int g = 0; g < 35; ++g) {
    const int slot = g & 1;
    do_phase(slot, 0, 0, g + 1, 0, 6);
    do_phase(slot, 0, 1, g + 1, 1, -1);
    do_phase(slot, 1, 0, g + 1, 2, 6);
    do_phase(slot, 1, 1, g + 1, 3, -1);
  }
  // tail group 35: no staging; drain progressively
  do_phase(1, 0, 0, -1, 0, 4);
  do_phase(1, 0, 1, -1, 0, -1);
  do_phase(1, 1, 0, -1, 0, 0);
  do_phase(1, 1, 1, -1, 0, -1);

  // epilogue: subtract w*dist, store raw scores
#pragma unroll
  for (int mi = 0; mi < 8; ++mi) {
    int m_t = wr * 128 + mi * 16 + ((lane >> 4) << 2);
#pragma unroll
    for (int j = 0; j < 4; ++j) {
      int n_t = wc * 64 + j * 16 + (lane & 15);
      float cjx = cco[2][n_t], cjy = cco[3][n_t];
      long rowbase = ((long)b * S_ + mt * 256 + m_t) * S_ + nt * 256 + n_t;
#pragma unroll
      for (int r = 0; r < 4; ++r) {
        float dx = cco[0][m_t + r] - cjx;
        float dy = cco[1][m_t + r] - cjy;
        float d = sqrtf(fmaxf(fmaf(dx, dx, dy * dy), 1e-12f));
        attn[rowbase + (long)r * S_] = acc[mi][j][r] - w * d;
      }
    }
  }
}

// ---------------------------------------------------------------------------
// K2b: row softmax in place. One wave per row.  [verbatim R1]
// ---------------------------------------------------------------------------
__global__ __launch_bounds__(256) void k_rowsoft(float* __restrict__ attn) {
  const int wid = threadIdx.x >> 6, lane = threadIdx.x & 63;
  float* p = attn + ((long)blockIdx.x * 4 + wid) * S_;
  float4 v[8];
#pragma unroll
  for (int i = 0; i < 8; ++i) v[i] = ((const float4*)p)[i * 64 + lane];
  float m = -3.4e38f;
#pragma unroll
  for (int i = 0; i < 8; ++i)
    m = fmaxf(m, fmaxf(fmaxf(v[i].x, v[i].y), fmaxf(v[i].z, v[i].w)));
#pragma unroll
  for (int o = 32; o > 0; o >>= 1) m = fmaxf(m, __shfl_xor(m, o));
  float l = 0.f;
#pragma unroll
  for (int i = 0; i < 8; ++i) {
    v[i].x = __expf(v[i].x - m);
    v[i].y = __expf(v[i].y - m);
    v[i].z = __expf(v[i].z - m);
    v[i].w = __expf(v[i].w - m);
    l += (v[i].x + v[i].y) + (v[i].z + v[i].w);
  }
#pragma unroll
  for (int o = 32; o > 0; o >>= 1) l += __shfl_xor(l, o);
  const float rl = 1.0f / l;
#pragma unroll
  for (int i = 0; i < 8; ++i) {
    v[i].x *= rl; v[i].y *= rl; v[i].z *= rl; v[i].w *= rl;
    ((float4*)p)[i * 64 + lane] = v[i];
  }
}

// ---------------------------------------------------------------------------
// K3: out = attn @ V. A reg-staged fp32->fp16, B = vT via global_load_lds.
// [verbatim R1]
// ---------------------------------------------------------------------------
__global__ __launch_bounds__(256, 2) void k_pv(
    const float* __restrict__ attn, const _Float16* __restrict__ vT,
    float* __restrict__ outp) {
  const int nt = blockIdx.x, mt = blockIdx.y, b = blockIdx.z;
  const int tid = threadIdx.x;
  __shared__ _Float16 sm[2][2][4096];
  f32x4 acc[4][4] = {};
  const float* Ab = attn + ((long)b * S_ + mt * 128) * S_;
  const _Float16* Bb = vT + ((long)b * H_ + nt * 128) * S_;
  const int lane = tid & 63, wid = tid >> 6;
  const int wm = (wid >> 1) * 64, wn = (wid & 1) * 64;

  stage_tile(Bb, S_, sm[0][1], tid);
#pragma unroll
  for (int seg = 0; seg < 2; ++seg) {
    int u = seg * 256 + tid, r = u >> 2, c = u & 3;
    int sc = c ^ ((r >> 1) & 3);
    const float4* s4 = (const float4*)(Ab + (long)r * S_ + sc * 8);
    float4 x0 = s4[0], x1 = s4[1];
    half8 h = {(_Float16)x0.x, (_Float16)x0.y, (_Float16)x0.z, (_Float16)x0.w,
               (_Float16)x1.x, (_Float16)x1.y, (_Float16)x1.z, (_Float16)x1.w};
    *(half8*)(&sm[0][0][r * 32 + c * 8]) = h;
  }
  __syncthreads();

  int cur = 0;
  for (int kk = 0; kk < 64; ++kk) {
    float4 x0a, x1a, x0b, x1b;
    const bool pre = (kk + 1 < 64);
    if (pre) {
      stage_tile(Bb + (kk + 1) * 32, S_, sm[cur ^ 1][1], tid);
      {
        int u = tid, r = u >> 2, sc = (u & 3) ^ ((r >> 1) & 3);
        const float4* s4 =
            (const float4*)(Ab + (long)r * S_ + (kk + 1) * 32 + sc * 8);
        x0a = s4[0]; x1a = s4[1];
      }
      {
        int u = 256 + tid, r = u >> 2, sc = (u & 3) ^ ((r >> 1) & 3);
        const float4* s4 =
            (const float4*)(Ab + (long)r * S_ + (kk + 1) * 32 + sc * 8);
        x0b = s4[0]; x1b = s4[1];
      }
    }
    half8 ah[4], bh[4];
#pragma unroll
    for (int i = 0; i < 4; ++i) ah[i] = frag(sm[cur][0], wm + i * 16, lane);
#pragma unroll
    for (int j = 0; j < 4; ++j) bh[j] = frag(sm[cur][1], wn + j * 16, lane);
#pragma unroll
    for (int i = 0; i < 4; ++i)
#pragma unroll
      for (int j = 0; j < 4; ++j)
        acc[i][j] = __builtin_amdgcn_mfma_f32_16x16x32_f16(ah[i], bh[j],
                                                           acc[i][j], 0, 0, 0);
    if (pre) {
      {
        int u = tid, r = u >> 2, c = u & 3;
        half8 h = {(_Float16)x0a.x, (_Float16)x0a.y, (_Float16)x0a.z,
                   (_Float16)x0a.w, (_Float16)x1a.x, (_Float16)x1a.y,
                   (_Float16)x1a.z, (_Float16)x1a.w};
        *(half8*)(&sm[cur ^ 1][0][r * 32 + c * 8]) = h;
      }
      {
        int u = 256 + tid, r = u >> 2, c = u & 3;
        half8 h = {(_Float16)x0b.x, (_Float16)x0b.y, (_Float16)x0b.z,
                   (_Float16)x0b.w, (_Float16)x1b.x, (_Float16)x1b.y,
                   (_Float16)x1b.z, (_Float16)x1b.w};
        *(half8*)(&sm[cur ^ 1][0][r * 32 + c * 8]) = h;
      }
    }
    __syncthreads();
    cur ^= 1;
  }

#pragma unroll
  for (int i = 0; i < 4; ++i) {
    int m_t = wm + i * 16 + ((lane >> 4) << 2);
#pragma unroll
    for (int j = 0; j < 4; ++j) {
      int n_t = wn + j * 16 + (lane & 15);
      int h = nt * 128 + n_t;
      long rowbase = (long)b * S_ + mt * 128 + m_t;
#pragma unroll
      for (int r = 0; r < 4; ++r) outp[(rowbase + r) * H_ + h] = acc[i][j][r];
    }
  }
}

// ---------------------------------------------------------------------------
extern "C" void kernel_launch(void* const* d_in, const int* in_sizes, int n_in,
                              void* d_out, int out_size, void* d_ws,
                              size_t ws_size, hipStream_t stream) {
  const float* xq = (const float*)d_in[0];
  const float* xk = (const float*)d_in[1];
  const float* xv = (const float*)d_in[2];
  const float* co = (const float*)d_in[3];
  const float* wq = (const float*)d_in[4];
  const float* bq = (const float*)d_in[5];
  const float* wk = (const float*)d_in[6];
  const float* bk = (const float*)d_in[7];
  const float* wv = (const float*)d_in[8];
  const float* bv = (const float*)d_in[9];
  const float* sw = (const float*)d_in[10];

  float* out = (float*)d_out;
  float* attn = out + NX;                // attn region of d_out
  _Float16* scratch = (_Float16*)d_out;  // K0/K1 scratch (dead before K2)

  _Float16* qh = (_Float16*)d_ws;
  _Float16* ql = qh + NX;
  _Float16* kh = ql + NX;
  _Float16* kl = kh + NX;
  _Float16* vT = kl + NX;

  k_split<<<dim3(2048), 256, 0, stream>>>(xq, xk, xv, wq, wk, wv, scratch);
  k_proj<<<dim3(6, 128, 3), 256, 0, stream>>>(scratch, bq, bk, bv, qh, ql, kh,
                                              kl, vT);
  k_scores8<<<dim3(8, 8, 8), 512, 0, stream>>>(qh, ql, kh, kl, co, sw, attn);
  k_rowsoft<<<dim3(4096), 256, 0, stream>>>(attn);
  k_pv<<<dim3(6, 16, 8), 256, 0, stream>>>(attn, vT, out);
}

// Round 5
// 537.231 us; speedup vs baseline: 1.1944x; 1.0311x over previous
//
#include <hip/hip_runtime.h>
#include <stdint.h>

// ---------------------------------------------------------------------------
// RichAttention: out = softmax(QK^T - w*cdist(coords)) @ V, attn also output.
// B=8, S=2048, H=768, fp32 in/out.
// R5: 4-kernel pipeline.
//   k_proj_fused: reads fp32 inputs directly, reg-stages hi/lo fp16 into LDS
//                 (fuses old k_split). Q,K -> hi/lo pairs; V -> transposed vT.
//   k_scores:     verbatim R1 128^2 3-term body (188us proven).
//   k_rowsoft:    softmax in place + normalized fp16 copy (a16).
//   k_pv16:       out = a16 @ vT^T, pure global_load_lds fp16 GEMM.
// ---------------------------------------------------------------------------

typedef _Float16 half8 __attribute__((ext_vector_type(8)));
typedef _Float16 half4v __attribute__((ext_vector_type(4)));
typedef float f32x4 __attribute__((ext_vector_type(4)));

#define DEVI static __device__ __forceinline__

constexpr int B_ = 8, S_ = 2048, H_ = 768;
constexpr long NX = (long)B_ * S_ * H_;   // 12,582,912
constexpr long NW = (long)H_ * H_;        // 589,824
constexpr long ATT = (long)B_ * S_ * S_;  // 33,554,432

// ---- async global->LDS, 16B per lane --------------------------------------
DEVI void glds16(const void* g, void* l) {
  __builtin_amdgcn_global_load_lds(
      (const __attribute__((address_space(1))) uint32_t*)g,
      (__attribute__((address_space(3))) uint32_t*)l, 16, 0, 0);
}

// Stage a [128][32]-fp16 tile (8KB). LDS slot (r,c) holds global chunk
// c ^ ((r>>1)&3). 256 threads x 2 units.
DEVI void stage_tile(const _Float16* gbase, int rowStride, _Float16* lds, int tid) {
#pragma unroll
  for (int seg = 0; seg < 2; ++seg) {
    int u = seg * 256 + tid;
    int r = u >> 2, c = u & 3;
    int sc = c ^ ((r >> 1) & 3);
    glds16(gbase + (long)r * rowStride + sc * 8, lds + ((u & ~63) << 3));
  }
}

// MFMA 16x16x32 A/B fragment read (undoes the chunk swizzle).
DEVI half8 frag(const _Float16* lds, int m0, int lane) {
  int row = m0 + (lane & 15);
  int c = (lane >> 4) ^ ((row >> 1) & 3);
  return *(const half8*)(lds + row * 32 + c * 8);
}

DEVI void split8(const float4& x0, const float4& x1, half8& hi, half8& lo) {
  float v[8] = {x0.x, x0.y, x0.z, x0.w, x1.x, x1.y, x1.z, x1.w};
#pragma unroll
  for (int k = 0; k < 8; ++k) {
    hi[k] = (_Float16)v[k];
    lo[k] = (_Float16)(v[k] - (float)hi[k]);
  }
}

// ---------------------------------------------------------------------------
// K1 (fused): projections Y = X @ W^T + b, reading fp32 X,W directly.
// z=0: Q -> qh/ql, z=1: K -> kh/kl (3-term needs hi/lo of both operands in
// LDS), z=2: V -> vT (single-term, hi only).
// Reg-staged: issue fp32 loads for step kk+1 before MFMA of kk, convert +
// ds_write after. Tile 128x128, BK=32, 4 waves.
// ---------------------------------------------------------------------------
__global__ __launch_bounds__(256, 2) void k_proj_fused(
    const float* __restrict__ xq, const float* __restrict__ xk,
    const float* __restrict__ xv, const float* __restrict__ wq,
    const float* __restrict__ wk, const float* __restrict__ wv,
    const float* __restrict__ bq, const float* __restrict__ bk,
    const float* __restrict__ bv, _Float16* __restrict__ qh,
    _Float16* __restrict__ ql, _Float16* __restrict__ kh,
    _Float16* __restrict__ kl, _Float16* __restrict__ vT) {
  const int nt = blockIdx.x, mt = blockIdx.y, z = blockIdx.z;
  const int tid = threadIdx.x;
  const bool full = (z < 2);
  const float* X = (z == 0) ? xq : (z == 1) ? xk : xv;
  const float* W = (z == 0) ? wq : (z == 1) ? wk : wv;
  const float* bias = (z == 0) ? bq : (z == 1) ? bk : bv;

  __shared__ _Float16 sm[2][4][4096];  // [buf][Ah,Al,Bh,Bl][128*32]
  f32x4 acc[4][4] = {};

  const float* Ab = X + (long)(mt * 128) * H_;
  const float* Bb = W + (long)(nt * 128) * H_;

  // per-thread (r, c, swizzled global col sc) for the 2 segments
  int rr[2], cc_[2], scc[2];
#pragma unroll
  for (int seg = 0; seg < 2; ++seg) {
    int u = seg * 256 + tid;
    rr[seg] = u >> 2;
    cc_[seg] = u & 3;
    scc[seg] = cc_[seg] ^ ((rr[seg] >> 1) & 3);
  }

  // stage buf 0 (k0 = 0)
#pragma unroll
  for (int seg = 0; seg < 2; ++seg) {
    const float4* sa = (const float4*)(Ab + (long)rr[seg] * H_ + scc[seg] * 8);
    const float4* sb = (const float4*)(Bb + (long)rr[seg] * H_ + scc[seg] * 8);
    half8 hi, lo, bhi, blo;
    split8(sa[0], sa[1], hi, lo);
    split8(sb[0], sb[1], bhi, blo);
    int off = rr[seg] * 32 + cc_[seg] * 8;
    *(half8*)(&sm[0][0][off]) = hi;
    *(half8*)(&sm[0][2][off]) = bhi;
    if (full) {
      *(half8*)(&sm[0][1][off]) = lo;
      *(half8*)(&sm[0][3][off]) = blo;
    }
  }
  __syncthreads();

  const int lane = tid & 63, wid = tid >> 6;
  const int wm = (wid >> 1) * 64, wn = (wid & 1) * 64;

  int cur = 0;
  for (int kk = 0; kk < 24; ++kk) {
    const bool pre = (kk + 1 < 24);
    float4 pa[2][2], pb[2][2];
    if (pre) {
      int o = (kk + 1) * 32;
#pragma unroll
      for (int seg = 0; seg < 2; ++seg) {
        const float4* sa =
            (const float4*)(Ab + (long)rr[seg] * H_ + o + scc[seg] * 8);
        pa[seg][0] = sa[0]; pa[seg][1] = sa[1];
        const float4* sb =
            (const float4*)(Bb + (long)rr[seg] * H_ + o + scc[seg] * 8);
        pb[seg][0] = sb[0]; pb[seg][1] = sb[1];
      }
    }
    half8 ah[4], bh[4];
#pragma unroll
    for (int i = 0; i < 4; ++i) ah[i] = frag(sm[cur][0], wm + i * 16, lane);
#pragma unroll
    for (int j = 0; j < 4; ++j) bh[j] = frag(sm[cur][2], wn + j * 16, lane);
#pragma unroll
    for (int i = 0; i < 4; ++i)
#pragma unroll
      for (int j = 0; j < 4; ++j)
        acc[i][j] = __builtin_amdgcn_mfma_f32_16x16x32_f16(ah[i], bh[j],
                                                           acc[i][j], 0, 0, 0);
    if (full) {
      half8 al[4], bl[4];
#pragma unroll
      for (int i = 0; i < 4; ++i) al[i] = frag(sm[cur][1], wm + i * 16, lane);
#pragma unroll
      for (int j = 0; j < 4; ++j) bl[j] = frag(sm[cur][3], wn + j * 16, lane);
#pragma unroll
      for (int i = 0; i < 4; ++i)
#pragma unroll
        for (int j = 0; j < 4; ++j) {
          acc[i][j] = __builtin_amdgcn_mfma_f32_16x16x32_f16(ah[i], bl[j],
                                                             acc[i][j], 0, 0, 0);
          acc[i][j] = __builtin_amdgcn_mfma_f32_16x16x32_f16(al[i], bh[j],
                                                             acc[i][j], 0, 0, 0);
        }
    }
    if (pre) {  // write-late
#pragma unroll
      for (int seg = 0; seg < 2; ++seg) {
        half8 hi, lo, bhi, blo;
        split8(pa[seg][0], pa[seg][1], hi, lo);
        split8(pb[seg][0], pb[seg][1], bhi, blo);
        int off = rr[seg] * 32 + cc_[seg] * 8;
        *(half8*)(&sm[cur ^ 1][0][off]) = hi;
        *(half8*)(&sm[cur ^ 1][2][off]) = bhi;
        if (full) {
          *(half8*)(&sm[cur ^ 1][1][off]) = lo;
          *(half8*)(&sm[cur ^ 1][3][off]) = blo;
        }
      }
    }
    __syncthreads();
    cur ^= 1;
  }

  // Epilogue. C/D layout: col = lane&15, row = (lane>>4)*4 + reg.
  _Float16* oh = (z == 0) ? qh : kh;
  _Float16* ol = (z == 0) ? ql : kl;
#pragma unroll
  for (int i = 0; i < 4; ++i) {
    int m_t = wm + i * 16 + ((lane >> 4) << 2);
#pragma unroll
    for (int j = 0; j < 4; ++j) {
      int n_t = wn + j * 16 + (lane & 15);
      int gn = nt * 128 + n_t;
      float bs = bias[gn];
      if (full) {
#pragma unroll
        for (int r = 0; r < 4; ++r) {
          long gm = (long)mt * 128 + m_t + r;
          float y = acc[i][j][r] + bs;
          _Float16 hi = (_Float16)y;
          oh[gm * H_ + gn] = hi;
          ol[gm * H_ + gn] = (_Float16)(y - (float)hi);
        }
      } else {
        int gmI = mt * 128 + m_t;
        int bb = gmI >> 11, t0 = gmI & 2047;
        half4v pk;
#pragma unroll
        for (int r = 0; r < 4; ++r) pk[r] = (_Float16)(acc[i][j][r] + bs);
        *(half4v*)&vT[((long)bb * H_ + gn) * S_ + t0] = pk;
      }
    }
  }
}

// ---------------------------------------------------------------------------
// K2: raw scores = q.k (3-term split-fp16) - w*dist.  [verbatim R1, 188us]
// ---------------------------------------------------------------------------
__global__ __launch_bounds__(256, 2) void k_scores(
    const _Float16* __restrict__ qh, const _Float16* __restrict__ ql,
    const _Float16* __restrict__ kh, const _Float16* __restrict__ kl,
    const float* __restrict__ coords, const float* __restrict__ sw,
    float* __restrict__ attn) {
  const int nt = blockIdx.x, mt = blockIdx.y, b = blockIdx.z;
  const int tid = threadIdx.x;
  __shared__ _Float16 sm[2][4][4096];
  __shared__ float cr[2][128], cc[2][128];

  if (tid < 128) {
    long gi = (long)b * S_ + mt * 128 + tid;
    cr[0][tid] = coords[gi * 2 + 0];
    cr[1][tid] = coords[gi * 2 + 1];
  } else {
    int t = tid - 128;
    long gj = (long)b * S_ + nt * 128 + t;
    cc[0][t] = coords[gj * 2 + 0];
    cc[1][t] = coords[gj * 2 + 1];
  }
  const float w = sw[0];

  f32x4 acc[4][4] = {};
  const long aoff = ((long)b * S_ + mt * 128) * H_;
  const long boff = ((long)b * S_ + nt * 128) * H_;
  const _Float16* Ah = qh + aoff;
  const _Float16* Al = ql + aoff;
  const _Float16* Bh = kh + boff;
  const _Float16* Bl = kl + boff;

  stage_tile(Ah, H_, sm[0][0], tid);
  stage_tile(Al, H_, sm[0][1], tid);
  stage_tile(Bh, H_, sm[0][2], tid);
  stage_tile(Bl, H_, sm[0][3], tid);
  __syncthreads();

  const int lane = tid & 63, wid = tid >> 6;
  const int wm = (wid >> 1) * 64, wn = (wid & 1) * 64;

  int cur = 0;
  for (int kk = 0; kk < 24; ++kk) {
    if (kk + 1 < 24) {
      int o = (kk + 1) * 32;
      stage_tile(Ah + o, H_, sm[cur ^ 1][0], tid);
      stage_tile(Al + o, H_, sm[cur ^ 1][1], tid);
      stage_tile(Bh + o, H_, sm[cur ^ 1][2], tid);
      stage_tile(Bl + o, H_, sm[cur ^ 1][3], tid);
    }
    half8 ah[4], al4[4], bh[4], bl4[4];
#pragma unroll
    for (int i = 0; i < 4; ++i) {
      ah[i] = frag(sm[cur][0], wm + i * 16, lane);
      al4[i] = frag(sm[cur][1], wm + i * 16, lane);
    }
#pragma unroll
    for (int j = 0; j < 4; ++j) {
      bh[j] = frag(sm[cur][2], wn + j * 16, lane);
      bl4[j] = frag(sm[cur][3], wn + j * 16, lane);
    }
#pragma unroll
    for (int i = 0; i < 4; ++i)
#pragma unroll
      for (int j = 0; j < 4; ++j) {
        acc[i][j] = __builtin_amdgcn_mfma_f32_16x16x32_f16(ah[i], bh[j],
                                                           acc[i][j], 0, 0, 0);
        acc[i][j] = __builtin_amdgcn_mfma_f32_16x16x32_f16(ah[i], bl4[j],
                                                           acc[i][j], 0, 0, 0);
        acc[i][j] = __builtin_amdgcn_mfma_f32_16x16x32_f16(al4[i], bh[j],
                                                           acc[i][j], 0, 0, 0);
      }
    __syncthreads();
    cur ^= 1;
  }

#pragma unroll
  for (int i = 0; i < 4; ++i) {
    int m_t = wm + i * 16 + ((lane >> 4) << 2);
#pragma unroll
    for (int j = 0; j < 4; ++j) {
      int n_t = wn + j * 16 + (lane & 15);
      float cjx = cc[0][n_t], cjy = cc[1][n_t];
      long rowbase = ((long)b * S_ + mt * 128 + m_t) * S_ + nt * 128 + n_t;
#pragma unroll
      for (int r = 0; r < 4; ++r) {
        float dx = cr[0][m_t + r] - cjx;
        float dy = cr[1][m_t + r] - cjy;
        float d = sqrtf(fmaxf(fmaf(dx, dx, dy * dy), 1e-12f));
        attn[rowbase + (long)r * S_] = acc[i][j][r] - w * d;
      }
    }
  }
}

// ---------------------------------------------------------------------------
// K2b: row softmax in place (fp32) + normalized fp16 copy for k_pv16.
// ---------------------------------------------------------------------------
__global__ __launch_bounds__(256) void k_rowsoft(float* __restrict__ attn,
                                                 _Float16* __restrict__ a16) {
  const int wid = threadIdx.x >> 6, lane = threadIdx.x & 63;
  long row = (long)blockIdx.x * 4 + wid;
  float* p = attn + row * S_;
  _Float16* p16 = a16 + row * S_;
  float4 v[8];
#pragma unroll
  for (int i = 0; i < 8; ++i) v[i] = ((const float4*)p)[i * 64 + lane];
  float m = -3.4e38f;
#pragma unroll
  for (int i = 0; i < 8; ++i)
    m = fmaxf(m, fmaxf(fmaxf(v[i].x, v[i].y), fmaxf(v[i].z, v[i].w)));
#pragma unroll
  for (int o = 32; o > 0; o >>= 1) m = fmaxf(m, __shfl_xor(m, o));
  float l = 0.f;
#pragma unroll
  for (int i = 0; i < 8; ++i) {
    v[i].x = __expf(v[i].x - m);
    v[i].y = __expf(v[i].y - m);
    v[i].z = __expf(v[i].z - m);
    v[i].w = __expf(v[i].w - m);
    l += (v[i].x + v[i].y) + (v[i].z + v[i].w);
  }
#pragma unroll
  for (int o = 32; o > 0; o >>= 1) l += __shfl_xor(l, o);
  const float rl = 1.0f / l;
#pragma unroll
  for (int i = 0; i < 8; ++i) {
    v[i].x *= rl; v[i].y *= rl; v[i].z *= rl; v[i].w *= rl;
    ((float4*)p)[i * 64 + lane] = v[i];
    half4v h = {(_Float16)v[i].x, (_Float16)v[i].y, (_Float16)v[i].z,
                (_Float16)v[i].w};
    ((half4v*)p16)[i * 64 + lane] = h;
  }
}

// ---------------------------------------------------------------------------
// K3: out = a16 @ vT^T. Pure global_load_lds fp16 pipeline, K=2048.
// ---------------------------------------------------------------------------
__global__ __launch_bounds__(256, 2) void k_pv16(
    const _Float16* __restrict__ a16, const _Float16* __restrict__ vT,
    float* __restrict__ outp) {
  const int nt = blockIdx.x, mt = blockIdx.y, b = blockIdx.z;
  const int tid = threadIdx.x, lane = tid & 63, wid = tid >> 6;
  const int wm = (wid >> 1) * 64, wn = (wid & 1) * 64;
  __shared__ _Float16 sm[2][2][4096];
  f32x4 acc[4][4] = {};
  const _Float16* Ab = a16 + ((long)b * S_ + mt * 128) * S_;
  const _Float16* Bb = vT + ((long)b * H_ + nt * 128) * S_;

  stage_tile(Ab, S_, sm[0][0], tid);
  stage_tile(Bb, S_, sm[0][1], tid);
  __syncthreads();

  int cur = 0;
  for (int kk = 0; kk < 64; ++kk) {
    if (kk + 1 < 64) {
      stage_tile(Ab + (kk + 1) * 32, S_, sm[cur ^ 1][0], tid);
      stage_tile(Bb + (kk + 1) * 32, S_, sm[cur ^ 1][1], tid);
    }
    half8 ah[4], bh[4];
#pragma unroll
    for (int i = 0; i < 4; ++i) ah[i] = frag(sm[cur][0], wm + i * 16, lane);
#pragma unroll
    for (int j = 0; j < 4; ++j) bh[j] = frag(sm[cur][1], wn + j * 16, lane);
#pragma unroll
    for (int i = 0; i < 4; ++i)
#pragma unroll
      for (int j = 0; j < 4; ++j)
        acc[i][j] = __builtin_amdgcn_mfma_f32_16x16x32_f16(ah[i], bh[j],
                                                           acc[i][j], 0, 0, 0);
    __syncthreads();
    cur ^= 1;
  }

#pragma unroll
  for (int i = 0; i < 4; ++i) {
    int m_t = wm + i * 16 + ((lane >> 4) << 2);
#pragma unroll
    for (int j = 0; j < 4; ++j) {
      int n_t = wn + j * 16 + (lane & 15);
      int h = nt * 128 + n_t;
      long rowbase = (long)b * S_ + mt * 128 + m_t;
#pragma unroll
      for (int r = 0; r < 4; ++r) outp[(rowbase + r) * H_ + h] = acc[i][j][r];
    }
  }
}

// ---------------------------------------------------------------------------
extern "C" void kernel_launch(void* const* d_in, const int* in_sizes, int n_in,
                              void* d_out, int out_size, void* d_ws,
                              size_t ws_size, hipStream_t stream) {
  const float* xq = (const float*)d_in[0];
  const float* xk = (const float*)d_in[1];
  const float* xv = (const float*)d_in[2];
  const float* co = (const float*)d_in[3];
  const float* wq = (const float*)d_in[4];
  const float* bq = (const float*)d_in[5];
  const float* wk = (const float*)d_in[6];
  const float* bk = (const float*)d_in[7];
  const float* wv = (const float*)d_in[8];
  const float* bv = (const float*)d_in[9];
  const float* sw = (const float*)d_in[10];

  float* out = (float*)d_out;
  float* attn = out + NX;

  // ws layout (125.8 MB, same footprint as R1):
  //   qh,ql,kh,kl: 4*NX halfs; vT: NX halfs (B*H*S).
  //   a16 (ATT halfs = 33.5M) aliases qh/ql/kh region, dead after k_scores.
  _Float16* qh = (_Float16*)d_ws;
  _Float16* ql = qh + NX;
  _Float16* kh = ql + NX;
  _Float16* kl = kh + NX;
  _Float16* vT = kl + NX;
  _Float16* a16 = qh;  // alias: written by k_rowsoft AFTER k_scores reads q/k

  k_proj_fused<<<dim3(6, 128, 3), 256, 0, stream>>>(xq, xk, xv, wq, wk, wv, bq,
                                                    bk, bv, qh, ql, kh, kl, vT);
  k_scores<<<dim3(16, 16, 8), 256, 0, stream>>>(qh, ql, kh, kl, co, sw, attn);
  k_rowsoft<<<dim3(4096), 256, 0, stream>>>(attn, a16);
  k_pv16<<<dim3(6, 16, 8), 256, 0, stream>>>(a16, vT, out);
}

// Round 6
// 522.808 us; speedup vs baseline: 1.2273x; 1.0276x over previous
//
#include <hip/hip_runtime.h>
#include <stdint.h>

// ---------------------------------------------------------------------------
// RichAttention: out = softmax(QK^T - w*cdist(coords)) @ V, attn also output.
// B=8, S=2048, H=768, fp32 in/out.
// R6: best-of-each-stage pipeline.
//   k_split:   Xq,Xk,Wq,Wk -> fp16 hi/lo; Xv,Wv -> fp16 hi only (d_out scratch)
//   k_proj:    R1-proven 128^2 global_load_lds GEMM. z=0,1: 3-term hi/lo out;
//              z=2: single-term V -> transposed vT.
//   k_scores:  R1-proven 3-term body (~188us, 822 TF eff).
//   k_rowsoft: softmax in place + normalized fp16 copy (a16).
//   k_pv16:    out = a16 @ vT^T, pure global_load_lds fp16 GEMM.
// ---------------------------------------------------------------------------

typedef _Float16 half8 __attribute__((ext_vector_type(8)));
typedef _Float16 half4v __attribute__((ext_vector_type(4)));
typedef float f32x4 __attribute__((ext_vector_type(4)));

#define DEVI static __device__ __forceinline__

constexpr int B_ = 8, S_ = 2048, H_ = 768;
constexpr long NX = (long)B_ * S_ * H_;   // 12,582,912
constexpr long NW = (long)H_ * H_;        // 589,824
constexpr long ATT = (long)B_ * S_ * S_;  // 33,554,432

// ---- async global->LDS, 16B per lane --------------------------------------
DEVI void glds16(const void* g, void* l) {
  __builtin_amdgcn_global_load_lds(
      (const __attribute__((address_space(1))) uint32_t*)g,
      (__attribute__((address_space(3))) uint32_t*)l, 16, 0, 0);
}

// Stage a [128][32]-fp16 tile (8KB). LDS slot (r,c) holds global chunk
// c ^ ((r>>1)&3). 256 threads x 2 units.
DEVI void stage_tile(const _Float16* gbase, int rowStride, _Float16* lds, int tid) {
#pragma unroll
  for (int seg = 0; seg < 2; ++seg) {
    int u = seg * 256 + tid;
    int r = u >> 2, c = u & 3;
    int sc = c ^ ((r >> 1) & 3);
    glds16(gbase + (long)r * rowStride + sc * 8, lds + ((u & ~63) << 3));
  }
}

// MFMA 16x16x32 A/B fragment read (undoes the chunk swizzle).
DEVI half8 frag(const _Float16* lds, int m0, int lane) {
  int row = m0 + (lane & 15);
  int c = (lane >> 4) ^ ((row >> 1) & 3);
  return *(const half8*)(lds + row * 32 + c * 8);
}

// ---------------------------------------------------------------------------
// K0: split. Xq,Xk -> hi/lo; Xv -> hi only; Wq,Wk -> hi/lo; Wv -> hi only.
// All fp16 into d_out scratch (dead until k_scores writes attn).
// Layout (halfs): [Xqh][Xql][Xkh][Xkl][Xvh] (5*NX)
//                 then [Wqh][Wql][Wkh][Wkl][Wvh] at 5*NX (+k*NW).
// ---------------------------------------------------------------------------
__global__ __launch_bounds__(256) void k_split(
    const float* __restrict__ xq, const float* __restrict__ xk,
    const float* __restrict__ xv, const float* __restrict__ wq,
    const float* __restrict__ wk, const float* __restrict__ wv,
    _Float16* __restrict__ dst) {
  const long NX4 = NX / 4, NW4 = NW / 4, TOT = 3 * NX4 + 3 * NW4;
  for (long u = (long)blockIdx.x * blockDim.x + threadIdx.x; u < TOT;
       u += (long)gridDim.x * blockDim.x) {
    const float4* src;
    _Float16 *dh, *dl;  // dl == nullptr-like sentinel via flag
    bool wantLo = true;
    long idx;
    if (u < 3 * NX4) {
      int z = (u >= 2 * NX4) ? 2 : (u >= NX4) ? 1 : 0;
      idx = u - (long)z * NX4;
      src = (const float4*)(z == 0 ? xq : z == 1 ? xk : xv);
      dh = dst + (long)z * 2 * NX;     // z=2 -> offset 4*NX (hi only)
      dl = dh + NX;
      wantLo = (z < 2);
    } else {
      long t = u - 3 * NX4;
      int z = (t >= 2 * NW4) ? 2 : (t >= NW4) ? 1 : 0;
      idx = t - (long)z * NW4;
      src = (const float4*)(z == 0 ? wq : z == 1 ? wk : wv);
      dh = dst + 5 * NX + (long)z * 2 * NW;  // z=2 -> 5*NX+4*NW (hi only)
      dl = dh + NW;
      wantLo = (z < 2);
    }
    float4 x = src[idx];
    half4v hi, lo;
    hi[0] = (_Float16)x.x; lo[0] = (_Float16)(x.x - (float)hi[0]);
    hi[1] = (_Float16)x.y; lo[1] = (_Float16)(x.y - (float)hi[1]);
    hi[2] = (_Float16)x.z; lo[2] = (_Float16)(x.z - (float)hi[2]);
    hi[3] = (_Float16)x.w; lo[3] = (_Float16)(x.w - (float)hi[3]);
    *(half4v*)(dh + idx * 4) = hi;
    if (wantLo) *(half4v*)(dl + idx * 4) = lo;
  }
}

// ---------------------------------------------------------------------------
// K1: projections Y = X @ W^T + b.  [verbatim R1 body]
// z=0: Q -> qh/ql (3-term), z=1: K -> kh/kl (3-term),
// z=2: V -> vT[b][h][t] fp16 (single-term).
// ---------------------------------------------------------------------------
__global__ __launch_bounds__(256, 2) void k_proj(
    const _Float16* __restrict__ scratch, const float* __restrict__ bq,
    const float* __restrict__ bk, const float* __restrict__ bv,
    _Float16* __restrict__ qh, _Float16* __restrict__ ql,
    _Float16* __restrict__ kh, _Float16* __restrict__ kl,
    _Float16* __restrict__ vT) {
  const int nt = blockIdx.x, mt = blockIdx.y, z = blockIdx.z;
  const int tid = threadIdx.x;
  const bool full = (z < 2);
  const _Float16* Xh = scratch + (long)z * 2 * NX;  // z=2 -> 4*NX (hi only)
  const _Float16* Xl = Xh + NX;
  const _Float16* Wh = scratch + 5 * NX + (long)z * 2 * NW;
  const _Float16* Wl = Wh + NW;
  const float* bias = (z == 0) ? bq : (z == 1) ? bk : bv;

  __shared__ _Float16 sm[2][4][4096];  // [buf][Ah,Al,Bh,Bl][128*32]

  f32x4 acc[4][4] = {};

  const _Float16* Ah = Xh + (long)(mt * 128) * H_;
  const _Float16* Al = Xl + (long)(mt * 128) * H_;
  const _Float16* Bh = Wh + (long)(nt * 128) * H_;
  const _Float16* Bl = Wl + (long)(nt * 128) * H_;

  stage_tile(Ah, H_, sm[0][0], tid);
  stage_tile(Bh, H_, sm[0][2], tid);
  if (full) {
    stage_tile(Al, H_, sm[0][1], tid);
    stage_tile(Bl, H_, sm[0][3], tid);
  }
  __syncthreads();

  const int lane = tid & 63, wid = tid >> 6;
  const int wm = (wid >> 1) * 64, wn = (wid & 1) * 64;

  int cur = 0;
  for (int kk = 0; kk < 24; ++kk) {
    if (kk + 1 < 24) {
      int o = (kk + 1) * 32;
      stage_tile(Ah + o, H_, sm[cur ^ 1][0], tid);
      stage_tile(Bh + o, H_, sm[cur ^ 1][2], tid);
      if (full) {
        stage_tile(Al + o, H_, sm[cur ^ 1][1], tid);
        stage_tile(Bl + o, H_, sm[cur ^ 1][3], tid);
      }
    }
    half8 ah[4], bh[4];
#pragma unroll
    for (int i = 0; i < 4; ++i) ah[i] = frag(sm[cur][0], wm + i * 16, lane);
#pragma unroll
    for (int j = 0; j < 4; ++j) bh[j] = frag(sm[cur][2], wn + j * 16, lane);
#pragma unroll
    for (int i = 0; i < 4; ++i)
#pragma unroll
      for (int j = 0; j < 4; ++j)
        acc[i][j] = __builtin_amdgcn_mfma_f32_16x16x32_f16(ah[i], bh[j],
                                                           acc[i][j], 0, 0, 0);
    if (full) {
      half8 al[4], bl[4];
#pragma unroll
      for (int i = 0; i < 4; ++i) al[i] = frag(sm[cur][1], wm + i * 16, lane);
#pragma unroll
      for (int j = 0; j < 4; ++j) bl[j] = frag(sm[cur][3], wn + j * 16, lane);
#pragma unroll
      for (int i = 0; i < 4; ++i)
#pragma unroll
        for (int j = 0; j < 4; ++j) {
          acc[i][j] = __builtin_amdgcn_mfma_f32_16x16x32_f16(ah[i], bl[j],
                                                             acc[i][j], 0, 0, 0);
          acc[i][j] = __builtin_amdgcn_mfma_f32_16x16x32_f16(al[i], bh[j],
                                                             acc[i][j], 0, 0, 0);
        }
    }
    __syncthreads();
    cur ^= 1;
  }

  _Float16* oh = (z == 0) ? qh : kh;
  _Float16* ol = (z == 0) ? ql : kl;
#pragma unroll
  for (int i = 0; i < 4; ++i) {
    int m_t = wm + i * 16 + ((lane >> 4) << 2);
#pragma unroll
    for (int j = 0; j < 4; ++j) {
      int n_t = wn + j * 16 + (lane & 15);
      int gn = nt * 128 + n_t;
      float bs = bias[gn];
      if (full) {
#pragma unroll
        for (int r = 0; r < 4; ++r) {
          long gm = (long)mt * 128 + m_t + r;
          float y = acc[i][j][r] + bs;
          _Float16 hi = (_Float16)y;
          oh[gm * H_ + gn] = hi;
          ol[gm * H_ + gn] = (_Float16)(y - (float)hi);
        }
      } else {
        int gmI = mt * 128 + m_t;
        int bb = gmI >> 11, t0 = gmI & 2047;
        half4v pk;
#pragma unroll
        for (int r = 0; r < 4; ++r) pk[r] = (_Float16)(acc[i][j][r] + bs);
        *(half4v*)&vT[((long)bb * H_ + gn) * S_ + t0] = pk;
      }
    }
  }
}

// ---------------------------------------------------------------------------
// K2: raw scores = q.k (3-term split-fp16) - w*dist.  [verbatim R1, ~188us]
// ---------------------------------------------------------------------------
__global__ __launch_bounds__(256, 2) void k_scores(
    const _Float16* __restrict__ qh, const _Float16* __restrict__ ql,
    const _Float16* __restrict__ kh, const _Float16* __restrict__ kl,
    const float* __restrict__ coords, const float* __restrict__ sw,
    float* __restrict__ attn) {
  const int nt = blockIdx.x, mt = blockIdx.y, b = blockIdx.z;
  const int tid = threadIdx.x;
  __shared__ _Float16 sm[2][4][4096];
  __shared__ float cr[2][128], cc[2][128];

  if (tid < 128) {
    long gi = (long)b * S_ + mt * 128 + tid;
    cr[0][tid] = coords[gi * 2 + 0];
    cr[1][tid] = coords[gi * 2 + 1];
  } else {
    int t = tid - 128;
    long gj = (long)b * S_ + nt * 128 + t;
    cc[0][t] = coords[gj * 2 + 0];
    cc[1][t] = coords[gj * 2 + 1];
  }
  const float w = sw[0];

  f32x4 acc[4][4] = {};
  const long aoff = ((long)b * S_ + mt * 128) * H_;
  const long boff = ((long)b * S_ + nt * 128) * H_;
  const _Float16* Ah = qh + aoff;
  const _Float16* Al = ql + aoff;
  const _Float16* Bh = kh + boff;
  const _Float16* Bl = kl + boff;

  stage_tile(Ah, H_, sm[0][0], tid);
  stage_tile(Al, H_, sm[0][1], tid);
  stage_tile(Bh, H_, sm[0][2], tid);
  stage_tile(Bl, H_, sm[0][3], tid);
  __syncthreads();

  const int lane = tid & 63, wid = tid >> 6;
  const int wm = (wid >> 1) * 64, wn = (wid & 1) * 64;

  int cur = 0;
  for (int kk = 0; kk < 24; ++kk) {
    if (kk + 1 < 24) {
      int o = (kk + 1) * 32;
      stage_tile(Ah + o, H_, sm[cur ^ 1][0], tid);
      stage_tile(Al + o, H_, sm[cur ^ 1][1], tid);
      stage_tile(Bh + o, H_, sm[cur ^ 1][2], tid);
      stage_tile(Bl + o, H_, sm[cur ^ 1][3], tid);
    }
    half8 ah[4], al4[4], bh[4], bl4[4];
#pragma unroll
    for (int i = 0; i < 4; ++i) {
      ah[i] = frag(sm[cur][0], wm + i * 16, lane);
      al4[i] = frag(sm[cur][1], wm + i * 16, lane);
    }
#pragma unroll
    for (int j = 0; j < 4; ++j) {
      bh[j] = frag(sm[cur][2], wn + j * 16, lane);
      bl4[j] = frag(sm[cur][3], wn + j * 16, lane);
    }
#pragma unroll
    for (int i = 0; i < 4; ++i)
#pragma unroll
      for (int j = 0; j < 4; ++j) {
        acc[i][j] = __builtin_amdgcn_mfma_f32_16x16x32_f16(ah[i], bh[j],
                                                           acc[i][j], 0, 0, 0);
        acc[i][j] = __builtin_amdgcn_mfma_f32_16x16x32_f16(ah[i], bl4[j],
                                                           acc[i][j], 0, 0, 0);
        acc[i][j] = __builtin_amdgcn_mfma_f32_16x16x32_f16(al4[i], bh[j],
                                                           acc[i][j], 0, 0, 0);
      }
    __syncthreads();
    cur ^= 1;
  }

#pragma unroll
  for (int i = 0; i < 4; ++i) {
    int m_t = wm + i * 16 + ((lane >> 4) << 2);
#pragma unroll
    for (int j = 0; j < 4; ++j) {
      int n_t = wn + j * 16 + (lane & 15);
      float cjx = cc[0][n_t], cjy = cc[1][n_t];
      long rowbase = ((long)b * S_ + mt * 128 + m_t) * S_ + nt * 128 + n_t;
#pragma unroll
      for (int r = 0; r < 4; ++r) {
        float dx = cr[0][m_t + r] - cjx;
        float dy = cr[1][m_t + r] - cjy;
        float d = sqrtf(fmaxf(fmaf(dx, dx, dy * dy), 1e-12f));
        attn[rowbase + (long)r * S_] = acc[i][j][r] - w * d;
      }
    }
  }
}

// ---------------------------------------------------------------------------
// K2b: row softmax in place (fp32) + normalized fp16 copy for k_pv16.
// ---------------------------------------------------------------------------
__global__ __launch_bounds__(256) void k_rowsoft(float* __restrict__ attn,
                                                 _Float16* __restrict__ a16) {
  const int wid = threadIdx.x >> 6, lane = threadIdx.x & 63;
  long row = (long)blockIdx.x * 4 + wid;
  float* p = attn + row * S_;
  _Float16* p16 = a16 + row * S_;
  float4 v[8];
#pragma unroll
  for (int i = 0; i < 8; ++i) v[i] = ((const float4*)p)[i * 64 + lane];
  float m = -3.4e38f;
#pragma unroll
  for (int i = 0; i < 8; ++i)
    m = fmaxf(m, fmaxf(fmaxf(v[i].x, v[i].y), fmaxf(v[i].z, v[i].w)));
#pragma unroll
  for (int o = 32; o > 0; o >>= 1) m = fmaxf(m, __shfl_xor(m, o));
  float l = 0.f;
#pragma unroll
  for (int i = 0; i < 8; ++i) {
    v[i].x = __expf(v[i].x - m);
    v[i].y = __expf(v[i].y - m);
    v[i].z = __expf(v[i].z - m);
    v[i].w = __expf(v[i].w - m);
    l += (v[i].x + v[i].y) + (v[i].z + v[i].w);
  }
#pragma unroll
  for (int o = 32; o > 0; o >>= 1) l += __shfl_xor(l, o);
  const float rl = 1.0f / l;
#pragma unroll
  for (int i = 0; i < 8; ++i) {
    v[i].x *= rl; v[i].y *= rl; v[i].z *= rl; v[i].w *= rl;
    ((float4*)p)[i * 64 + lane] = v[i];
    half4v h = {(_Float16)v[i].x, (_Float16)v[i].y, (_Float16)v[i].z,
                (_Float16)v[i].w};
    ((half4v*)p16)[i * 64 + lane] = h;
  }
}

// ---------------------------------------------------------------------------
// K3: out = a16 @ vT^T. Pure global_load_lds fp16 pipeline, K=2048.
// ---------------------------------------------------------------------------
__global__ __launch_bounds__(256, 2) void k_pv16(
    const _Float16* __restrict__ a16, const _Float16* __restrict__ vT,
    float* __restrict__ outp) {
  const int nt = blockIdx.x, mt = blockIdx.y, b = blockIdx.z;
  const int tid = threadIdx.x, lane = tid & 63, wid = tid >> 6;
  const int wm = (wid >> 1) * 64, wn = (wid & 1) * 64;
  __shared__ _Float16 sm[2][2][4096];
  f32x4 acc[4][4] = {};
  const _Float16* Ab = a16 + ((long)b * S_ + mt * 128) * S_;
  const _Float16* Bb = vT + ((long)b * H_ + nt * 128) * S_;

  stage_tile(Ab, S_, sm[0][0], tid);
  stage_tile(Bb, S_, sm[0][1], tid);
  __syncthreads();

  int cur = 0;
  for (int kk = 0; kk < 64; ++kk) {
    if (kk + 1 < 64) {
      stage_tile(Ab + (kk + 1) * 32, S_, sm[cur ^ 1][0], tid);
      stage_tile(Bb + (kk + 1) * 32, S_, sm[cur ^ 1][1], tid);
    }
    half8 ah[4], bh[4];
#pragma unroll
    for (int i = 0; i < 4; ++i) ah[i] = frag(sm[cur][0], wm + i * 16, lane);
#pragma unroll
    for (int j = 0; j < 4; ++j) bh[j] = frag(sm[cur][1], wn + j * 16, lane);
#pragma unroll
    for (int i = 0; i < 4; ++i)
#pragma unroll
      for (int j = 0; j < 4; ++j)
        acc[i][j] = __builtin_amdgcn_mfma_f32_16x16x32_f16(ah[i], bh[j],
                                                           acc[i][j], 0, 0, 0);
    __syncthreads();
    cur ^= 1;
  }

#pragma unroll
  for (int i = 0; i < 4; ++i) {
    int m_t = wm + i * 16 + ((lane >> 4) << 2);
#pragma unroll
    for (int j = 0; j < 4; ++j) {
      int n_t = wn + j * 16 + (lane & 15);
      int h = nt * 128 + n_t;
      long rowbase = (long)b * S_ + mt * 128 + m_t;
#pragma unroll
      for (int r = 0; r < 4; ++r) outp[(rowbase + r) * H_ + h] = acc[i][j][r];
    }
  }
}

// ---------------------------------------------------------------------------
extern "C" void kernel_launch(void* const* d_in, const int* in_sizes, int n_in,
                              void* d_out, int out_size, void* d_ws,
                              size_t ws_size, hipStream_t stream) {
  const float* xq = (const float*)d_in[0];
  const float* xk = (const float*)d_in[1];
  const float* xv = (const float*)d_in[2];
  const float* co = (const float*)d_in[3];
  const float* wq = (const float*)d_in[4];
  const float* bq = (const float*)d_in[5];
  const float* wk = (const float*)d_in[6];
  const float* bk = (const float*)d_in[7];
  const float* wv = (const float*)d_in[8];
  const float* bv = (const float*)d_in[9];
  const float* sw = (const float*)d_in[10];

  float* out = (float*)d_out;
  float* attn = out + NX;                // attn region of d_out
  _Float16* scratch = (_Float16*)d_out;  // split outputs (dead before k_scores)

  // ws (125.8 MB): qh,ql,kh,kl,vT (NX halfs each).
  // a16 (ATT=33.5M halfs) aliases qh..kh region, dead after k_scores.
  _Float16* qh = (_Float16*)d_ws;
  _Float16* ql = qh + NX;
  _Float16* kh = ql + NX;
  _Float16* kl = kh + NX;
  _Float16* vT = kl + NX;
  _Float16* a16 = qh;

  k_split<<<dim3(2048), 256, 0, stream>>>(xq, xk, xv, wq, wk, wv, scratch);
  k_proj<<<dim3(6, 128, 3), 256, 0, stream>>>(scratch, bq, bk, bv, qh, ql, kh,
                                              kl, vT);
  k_scores<<<dim3(16, 16, 8), 256, 0, stream>>>(qh, ql, kh, kl, co, sw, attn);
  k_rowsoft<<<dim3(4096), 256, 0, stream>>>(attn, a16);
  k_pv16<<<dim3(6, 16, 8), 256, 0, stream>>>(a16, vT, out);
}

// Round 7
// 505.041 us; speedup vs baseline: 1.2705x; 1.0352x over previous
//
#include <hip/hip_runtime.h>
#include <stdint.h>

// ---------------------------------------------------------------------------
// RichAttention: out = softmax(QK^T - w*cdist(coords)) @ V, attn also output.
// B=8, S=2048, H=768, fp32 in/out.
// R7 = R6 with k_scores replaced by a faithful m201-style 8-phase port:
//   256x256 tile, BK=64, 8 waves (2x4), LDS [2 slot][2 khalf][A,B][256x32],
//   ko-major virtual-K (single pass over K), prefetch D=7 half-tiles,
//   vmcnt(6) once per tile at its LAST phase (guards next tile),
//   per-phase {ds-load, stage, barrier, lgkmcnt(0), 16 MFMA, barrier}.
// ---------------------------------------------------------------------------

typedef _Float16 half8 __attribute__((ext_vector_type(8)));
typedef _Float16 half4v __attribute__((ext_vector_type(4)));
typedef float f32x4 __attribute__((ext_vector_type(4)));

#define DEVI static __device__ __forceinline__

constexpr int B_ = 8, S_ = 2048, H_ = 768;
constexpr long NX = (long)B_ * S_ * H_;   // 12,582,912
constexpr long NW = (long)H_ * H_;        // 589,824
constexpr long ATT = (long)B_ * S_ * S_;  // 33,554,432

// ---- async global->LDS, 16B per lane --------------------------------------
DEVI void glds16(const void* g, void* l) {
  __builtin_amdgcn_global_load_lds(
      (const __attribute__((address_space(1))) uint32_t*)g,
      (__attribute__((address_space(3))) uint32_t*)l, 16, 0, 0);
}

// Stage a [128][32]-fp16 tile (8KB). LDS slot (r,c) holds global chunk
// c ^ ((r>>1)&3). 256 threads x 2 units.
DEVI void stage_tile(const _Float16* gbase, int rowStride, _Float16* lds, int tid) {
#pragma unroll
  for (int seg = 0; seg < 2; ++seg) {
    int u = seg * 256 + tid;
    int r = u >> 2, c = u & 3;
    int sc = c ^ ((r >> 1) & 3);
    glds16(gbase + (long)r * rowStride + sc * 8, lds + ((u & ~63) << 3));
  }
}

// MFMA 16x16x32 A/B fragment read (undoes the chunk swizzle).
DEVI half8 frag(const _Float16* lds, int m0, int lane) {
  int row = m0 + (lane & 15);
  int c = (lane >> 4) ^ ((row >> 1) & 3);
  return *(const half8*)(lds + row * 32 + c * 8);
}

// ---------------------------------------------------------------------------
// K0: split. Xq,Xk -> hi/lo; Xv -> hi only; Wq,Wk -> hi/lo; Wv -> hi only.
// ---------------------------------------------------------------------------
__global__ __launch_bounds__(256) void k_split(
    const float* __restrict__ xq, const float* __restrict__ xk,
    const float* __restrict__ xv, const float* __restrict__ wq,
    const float* __restrict__ wk, const float* __restrict__ wv,
    _Float16* __restrict__ dst) {
  const long NX4 = NX / 4, NW4 = NW / 4, TOT = 3 * NX4 + 3 * NW4;
  for (long u = (long)blockIdx.x * blockDim.x + threadIdx.x; u < TOT;
       u += (long)gridDim.x * blockDim.x) {
    const float4* src;
    _Float16 *dh, *dl;
    bool wantLo = true;
    long idx;
    if (u < 3 * NX4) {
      int z = (u >= 2 * NX4) ? 2 : (u >= NX4) ? 1 : 0;
      idx = u - (long)z * NX4;
      src = (const float4*)(z == 0 ? xq : z == 1 ? xk : xv);
      dh = dst + (long)z * 2 * NX;
      dl = dh + NX;
      wantLo = (z < 2);
    } else {
      long t = u - 3 * NX4;
      int z = (t >= 2 * NW4) ? 2 : (t >= NW4) ? 1 : 0;
      idx = t - (long)z * NW4;
      src = (const float4*)(z == 0 ? wq : z == 1 ? wk : wv);
      dh = dst + 5 * NX + (long)z * 2 * NW;
      dl = dh + NW;
      wantLo = (z < 2);
    }
    float4 x = src[idx];
    half4v hi, lo;
    hi[0] = (_Float16)x.x; lo[0] = (_Float16)(x.x - (float)hi[0]);
    hi[1] = (_Float16)x.y; lo[1] = (_Float16)(x.y - (float)hi[1]);
    hi[2] = (_Float16)x.z; lo[2] = (_Float16)(x.z - (float)hi[2]);
    hi[3] = (_Float16)x.w; lo[3] = (_Float16)(x.w - (float)hi[3]);
    *(half4v*)(dh + idx * 4) = hi;
    if (wantLo) *(half4v*)(dl + idx * 4) = lo;
  }
}

// ---------------------------------------------------------------------------
// K1: projections Y = X @ W^T + b.  [verbatim R1/R6 body]
// ---------------------------------------------------------------------------
__global__ __launch_bounds__(256, 2) void k_proj(
    const _Float16* __restrict__ scratch, const float* __restrict__ bq,
    const float* __restrict__ bk, const float* __restrict__ bv,
    _Float16* __restrict__ qh, _Float16* __restrict__ ql,
    _Float16* __restrict__ kh, _Float16* __restrict__ kl,
    _Float16* __restrict__ vT) {
  const int nt = blockIdx.x, mt = blockIdx.y, z = blockIdx.z;
  const int tid = threadIdx.x;
  const bool full = (z < 2);
  const _Float16* Xh = scratch + (long)z * 2 * NX;
  const _Float16* Xl = Xh + NX;
  const _Float16* Wh = scratch + 5 * NX + (long)z * 2 * NW;
  const _Float16* Wl = Wh + NW;
  const float* bias = (z == 0) ? bq : (z == 1) ? bk : bv;

  __shared__ _Float16 sm[2][4][4096];
  f32x4 acc[4][4] = {};

  const _Float16* Ah = Xh + (long)(mt * 128) * H_;
  const _Float16* Al = Xl + (long)(mt * 128) * H_;
  const _Float16* Bh = Wh + (long)(nt * 128) * H_;
  const _Float16* Bl = Wl + (long)(nt * 128) * H_;

  stage_tile(Ah, H_, sm[0][0], tid);
  stage_tile(Bh, H_, sm[0][2], tid);
  if (full) {
    stage_tile(Al, H_, sm[0][1], tid);
    stage_tile(Bl, H_, sm[0][3], tid);
  }
  __syncthreads();

  const int lane = tid & 63, wid = tid >> 6;
  const int wm = (wid >> 1) * 64, wn = (wid & 1) * 64;

  int cur = 0;
  for (int kk = 0; kk < 24; ++kk) {
    if (kk + 1 < 24) {
      int o = (kk + 1) * 32;
      stage_tile(Ah + o, H_, sm[cur ^ 1][0], tid);
      stage_tile(Bh + o, H_, sm[cur ^ 1][2], tid);
      if (full) {
        stage_tile(Al + o, H_, sm[cur ^ 1][1], tid);
        stage_tile(Bl + o, H_, sm[cur ^ 1][3], tid);
      }
    }
    half8 ah[4], bh[4];
#pragma unroll
    for (int i = 0; i < 4; ++i) ah[i] = frag(sm[cur][0], wm + i * 16, lane);
#pragma unroll
    for (int j = 0; j < 4; ++j) bh[j] = frag(sm[cur][2], wn + j * 16, lane);
#pragma unroll
    for (int i = 0; i < 4; ++i)
#pragma unroll
      for (int j = 0; j < 4; ++j)
        acc[i][j] = __builtin_amdgcn_mfma_f32_16x16x32_f16(ah[i], bh[j],
                                                           acc[i][j], 0, 0, 0);
    if (full) {
      half8 al[4], bl[4];
#pragma unroll
      for (int i = 0; i < 4; ++i) al[i] = frag(sm[cur][1], wm + i * 16, lane);
#pragma unroll
      for (int j = 0; j < 4; ++j) bl[j] = frag(sm[cur][3], wn + j * 16, lane);
#pragma unroll
      for (int i = 0; i < 4; ++i)
#pragma unroll
        for (int j = 0; j < 4; ++j) {
          acc[i][j] = __builtin_amdgcn_mfma_f32_16x16x32_f16(ah[i], bl[j],
                                                             acc[i][j], 0, 0, 0);
          acc[i][j] = __builtin_amdgcn_mfma_f32_16x16x32_f16(al[i], bh[j],
                                                             acc[i][j], 0, 0, 0);
        }
    }
    __syncthreads();
    cur ^= 1;
  }

  _Float16* oh = (z == 0) ? qh : kh;
  _Float16* ol = (z == 0) ? ql : kl;
#pragma unroll
  for (int i = 0; i < 4; ++i) {
    int m_t = wm + i * 16 + ((lane >> 4) << 2);
#pragma unroll
    for (int j = 0; j < 4; ++j) {
      int n_t = wn + j * 16 + (lane & 15);
      int gn = nt * 128 + n_t;
      float bs = bias[gn];
      if (full) {
#pragma unroll
        for (int r = 0; r < 4; ++r) {
          long gm = (long)mt * 128 + m_t + r;
          float y = acc[i][j][r] + bs;
          _Float16 hi = (_Float16)y;
          oh[gm * H_ + gn] = hi;
          ol[gm * H_ + gn] = (_Float16)(y - (float)hi);
        }
      } else {
        int gmI = mt * 128 + m_t;
        int bb = gmI >> 11, t0 = gmI & 2047;
        half4v pk;
#pragma unroll
        for (int r = 0; r < 4; ++r) pk[r] = (_Float16)(acc[i][j][r] + bs);
        *(half4v*)&vT[((long)bb * H_ + gn) * S_ + t0] = pk;
      }
    }
  }
}

// ---------------------------------------------------------------------------
// K2 (R7): raw scores = q.k (3-term split-fp16) - w*dist.
// 8-phase m201-style schedule; see header comment. Virtual-K ko-major:
// tile t: ko = (t/3)*64, term = t%3 -> (qh,kh),(qh,kl),(ql,kh).
// 36 tiles of 64; half-tile h (4/tile): kind {A.k0,B.k0,A.k1,B.k1}.
// ---------------------------------------------------------------------------
__global__ __launch_bounds__(512, 2) void k_scores8p(
    const _Float16* __restrict__ qh, const _Float16* __restrict__ ql,
    const _Float16* __restrict__ kh_, const _Float16* __restrict__ kl_,
    const float* __restrict__ coords, const float* __restrict__ sw,
    float* __restrict__ attn) {
  const int nt = blockIdx.x, mt = blockIdx.y, b = blockIdx.z;
  const int tid = threadIdx.x, lane = tid & 63, wid = tid >> 6;
  const int wr = wid >> 2, wc = wid & 3;  // 2x4 waves, each 128x64 out

  __shared__ _Float16 lds[2][2][2][8192];  // [slot][khalf][A,B][256*32]
  __shared__ float cco[4][256];

  if (tid < 256) {
    long gi = (long)b * S_ + mt * 256 + tid;
    cco[0][tid] = coords[gi * 2 + 0];
    cco[1][tid] = coords[gi * 2 + 1];
  } else {
    int t = tid - 256;
    long gj = (long)b * S_ + nt * 256 + t;
    cco[2][t] = coords[gj * 2 + 0];
    cco[3][t] = coords[gj * 2 + 1];
  }
  const float w = sw[0];

  const long aoff = ((long)b * S_ + mt * 256) * H_;
  const long boff = ((long)b * S_ + nt * 256) * H_;

  // staging map: 512 threads x 2 units cover 256 rows x 32 cols fp16
  long goff[2];
  int loff[2];
#pragma unroll
  for (int seg = 0; seg < 2; ++seg) {
    int u = seg * 512 + tid;
    int r = u >> 2, c = u & 3;
    int sc = c ^ ((r >> 1) & 3);
    goff[seg] = (long)r * H_ + sc * 8;
    loff[seg] = (u & ~63) << 3;
  }

  f32x4 acc[8][4] = {};

  // stage one half-tile h (2 glds16/thread)
  auto stage_half = [&](int h) {
    int th = h >> 2, kind = h & 3;
    int khf = kind >> 1, mx = kind & 1;
    int term = th % 3;
    long ko = (long)(th / 3) * 64 + khf * 32;
    const _Float16* src = mx ? ((term == 1 ? kl_ : kh_) + boff + ko)
                             : ((term == 2 ? ql : qh) + aoff + ko);
    _Float16* dst = &lds[th & 1][khf][mx][0];
    glds16(src + goff[0], dst + loff[0]);
    glds16(src + goff[1], dst + loff[1]);
  };

  half8 bf[4];  // B-frags persist across the mh pair within a khalf

  // One phase. vm: -1 none, 6 steady-state, 0 tail drain. hst: half to stage
  // (-1 none). Order = template: ds-load, stage, [vmcnt], barrier,
  // lgkmcnt(0)+sched_barrier, setprio(1), 16 MFMA, setprio(0), barrier.
  auto phase = [&](int slot, int kh, int mh, int hst, int vm) {
    const _Float16* A = &lds[slot][kh][0][0];
    const _Float16* Bt = &lds[slot][kh][1][0];
    half8 af[4];
    if (mh == 0) {
#pragma unroll
      for (int j = 0; j < 4; ++j) bf[j] = frag(Bt, wc * 64 + j * 16, lane);
    }
#pragma unroll
    for (int i = 0; i < 4; ++i)
      af[i] = frag(A, wr * 128 + mh * 64 + i * 16, lane);
    if (hst >= 0) stage_half(hst);
    if (vm == 6) asm volatile("s_waitcnt vmcnt(6)" ::: "memory");
    else if (vm == 0) asm volatile("s_waitcnt vmcnt(0)" ::: "memory");
    __builtin_amdgcn_s_barrier();
    asm volatile("s_waitcnt lgkmcnt(0)" ::: "memory");
    __builtin_amdgcn_sched_barrier(0);
    __builtin_amdgcn_s_setprio(1);
#pragma unroll
    for (int i = 0; i < 4; ++i)
#pragma unroll
      for (int j = 0; j < 4; ++j)
        acc[mh * 4 + i][j] = __builtin_amdgcn_mfma_f32_16x16x32_f16(
            af[i], bf[j], acc[mh * 4 + i][j], 0, 0, 0);
    __builtin_amdgcn_s_setprio(0);
    asm volatile("" ::: "memory");
    __builtin_amdgcn_s_barrier();
  };

  // prologue: stage halves 0..6 (D=7); vmcnt(6) -> halves 0..3 (tile 0) landed
#pragma unroll
  for (int h = 0; h < 7; ++h) stage_half(h);
  asm volatile("s_waitcnt vmcnt(6)" ::: "memory");
  __builtin_amdgcn_s_barrier();

  // main: tiles 0..33, vmcnt(6) at each tile's last phase guards tile t+1
#pragma unroll 1
  for (int t = 0; t < 34; ++t) {
    const int slot = t & 1, P = 4 * t;
    phase(slot, 0, 0, P + 7, -1);
    phase(slot, 0, 1, P + 8, -1);
    phase(slot, 1, 0, P + 9, -1);
    phase(slot, 1, 1, P + 10 <= 143 ? P + 10 : -1, 6);
  }
  // tile 34: stages the final half (h=143) at its first phase; vmcnt(0) at its
  // last phase guards tile 35 (all loads issued by then).
  phase(0, 0, 0, 143, -1);
  phase(0, 0, 1, -1, -1);
  phase(0, 1, 0, -1, -1);
  phase(0, 1, 1, -1, 0);
  // tile 35: all data landed; no staging, no waits.
  phase(1, 0, 0, -1, -1);
  phase(1, 0, 1, -1, -1);
  phase(1, 1, 0, -1, -1);
  phase(1, 1, 1, -1, -1);

  // epilogue: subtract w*dist, store raw scores
#pragma unroll
  for (int mi = 0; mi < 8; ++mi) {
    int m_t = wr * 128 + mi * 16 + ((lane >> 4) << 2);
#pragma unroll
    for (int j = 0; j < 4; ++j) {
      int n_t = wc * 64 + j * 16 + (lane & 15);
      float cjx = cco[2][n_t], cjy = cco[3][n_t];
      long rowbase = ((long)b * S_ + mt * 256 + m_t) * S_ + nt * 256 + n_t;
#pragma unroll
      for (int r = 0; r < 4; ++r) {
        float dx = cco[0][m_t + r] - cjx;
        float dy = cco[1][m_t + r] - cjy;
        float d = sqrtf(fmaxf(fmaf(dx, dx, dy * dy), 1e-12f));
        attn[rowbase + (long)r * S_] = acc[mi][j][r] - w * d;
      }
    }
  }
}

// ---------------------------------------------------------------------------
// K2b: row softmax in place (fp32) + normalized fp16 copy for k_pv16.
// ---------------------------------------------------------------------------
__global__ __launch_bounds__(256) void k_rowsoft(float* __restrict__ attn,
                                                 _Float16* __restrict__ a16) {
  const int wid = threadIdx.x >> 6, lane = threadIdx.x & 63;
  long row = (long)blockIdx.x * 4 + wid;
  float* p = attn + row * S_;
  _Float16* p16 = a16 + row * S_;
  float4 v[8];
#pragma unroll
  for (int i = 0; i < 8; ++i) v[i] = ((const float4*)p)[i * 64 + lane];
  float m = -3.4e38f;
#pragma unroll
  for (int i = 0; i < 8; ++i)
    m = fmaxf(m, fmaxf(fmaxf(v[i].x, v[i].y), fmaxf(v[i].z, v[i].w)));
#pragma unroll
  for (int o = 32; o > 0; o >>= 1) m = fmaxf(m, __shfl_xor(m, o));
  float l = 0.f;
#pragma unroll
  for (int i = 0; i < 8; ++i) {
    v[i].x = __expf(v[i].x - m);
    v[i].y = __expf(v[i].y - m);
    v[i].z = __expf(v[i].z - m);
    v[i].w = __expf(v[i].w - m);
    l += (v[i].x + v[i].y) + (v[i].z + v[i].w);
  }
#pragma unroll
  for (int o = 32; o > 0; o >>= 1) l += __shfl_xor(l, o);
  const float rl = 1.0f / l;
#pragma unroll
  for (int i = 0; i < 8; ++i) {
    v[i].x *= rl; v[i].y *= rl; v[i].z *= rl; v[i].w *= rl;
    ((float4*)p)[i * 64 + lane] = v[i];
    half4v h = {(_Float16)v[i].x, (_Float16)v[i].y, (_Float16)v[i].z,
                (_Float16)v[i].w};
    ((half4v*)p16)[i * 64 + lane] = h;
  }
}

// ---------------------------------------------------------------------------
// K3: out = a16 @ vT^T. Pure global_load_lds fp16 pipeline, K=2048.
// ---------------------------------------------------------------------------
__global__ __launch_bounds__(256, 2) void k_pv16(
    const _Float16* __restrict__ a16, const _Float16* __restrict__ vT,
    float* __restrict__ outp) {
  const int nt = blockIdx.x, mt = blockIdx.y, b = blockIdx.z;
  const int tid = threadIdx.x, lane = tid & 63, wid = tid >> 6;
  const int wm = (wid >> 1) * 64, wn = (wid & 1) * 64;
  __shared__ _Float16 sm[2][2][4096];
  f32x4 acc[4][4] = {};
  const _Float16* Ab = a16 + ((long)b * S_ + mt * 128) * S_;
  const _Float16* Bb = vT + ((long)b * H_ + nt * 128) * S_;

  stage_tile(Ab, S_, sm[0][0], tid);
  stage_tile(Bb, S_, sm[0][1], tid);
  __syncthreads();

  int cur = 0;
  for (int kk = 0; kk < 64; ++kk) {
    if (kk + 1 < 64) {
      stage_tile(Ab + (kk + 1) * 32, S_, sm[cur ^ 1][0], tid);
      stage_tile(Bb + (kk + 1) * 32, S_, sm[cur ^ 1][1], tid);
    }
    half8 ah[4], bh[4];
#pragma unroll
    for (int i = 0; i < 4; ++i) ah[i] = frag(sm[cur][0], wm + i * 16, lane);
#pragma unroll
    for (int j = 0; j < 4; ++j) bh[j] = frag(sm[cur][1], wn + j * 16, lane);
#pragma unroll
    for (int i = 0; i < 4; ++i)
#pragma unroll
      for (int j = 0; j < 4; ++j)
        acc[i][j] = __builtin_amdgcn_mfma_f32_16x16x32_f16(ah[i], bh[j],
                                                           acc[i][j], 0, 0, 0);
    __syncthreads();
    cur ^= 1;
  }

#pragma unroll
  for (int i = 0; i < 4; ++i) {
    int m_t = wm + i * 16 + ((lane >> 4) << 2);
#pragma unroll
    for (int j = 0; j < 4; ++j) {
      int n_t = wn + j * 16 + (lane & 15);
      int h = nt * 128 + n_t;
      long rowbase = (long)b * S_ + mt * 128 + m_t;
#pragma unroll
      for (int r = 0; r < 4; ++r) outp[(rowbase + r) * H_ + h] = acc[i][j][r];
    }
  }
}

// ---------------------------------------------------------------------------
extern "C" void kernel_launch(void* const* d_in, const int* in_sizes, int n_in,
                              void* d_out, int out_size, void* d_ws,
                              size_t ws_size, hipStream_t stream) {
  const float* xq = (const float*)d_in[0];
  const float* xk = (const float*)d_in[1];
  const float* xv = (const float*)d_in[2];
  const float* co = (const float*)d_in[3];
  const float* wq = (const float*)d_in[4];
  const float* bq = (const float*)d_in[5];
  const float* wk = (const float*)d_in[6];
  const float* bk = (const float*)d_in[7];
  const float* wv = (const float*)d_in[8];
  const float* bv = (const float*)d_in[9];
  const float* sw = (const float*)d_in[10];

  float* out = (float*)d_out;
  float* attn = out + NX;
  _Float16* scratch = (_Float16*)d_out;

  _Float16* qh = (_Float16*)d_ws;
  _Float16* ql = qh + NX;
  _Float16* kh = ql + NX;
  _Float16* kl = kh + NX;
  _Float16* vT = kl + NX;
  _Float16* a16 = qh;

  k_split<<<dim3(2048), 256, 0, stream>>>(xq, xk, xv, wq, wk, wv, scratch);
  k_proj<<<dim3(6, 128, 3), 256, 0, stream>>>(scratch, bq, bk, bv, qh, ql, kh,
                                              kl, vT);
  k_scores8p<<<dim3(8, 8, 8), 512, 0, stream>>>(qh, ql, kh, kl, co, sw, attn);
  k_rowsoft<<<dim3(4096), 256, 0, stream>>>(attn, a16);
  k_pv16<<<dim3(6, 16, 8), 256, 0, stream>>>(a16, vT, out);
}